// Round 12
// baseline (758.376 us; speedup 1.0000x reference)
//
#include <hip/hip_runtime.h>
#include <hip/hip_bf16.h>
#include <math.h>

#define GG 256
#define NP 24
#define LL 3
#define CC 256
#define NN (GG*NP)   // 6144 nodes
#define HH 4
#define DH 64

typedef __hip_bfloat16 bf;
typedef __attribute__((ext_vector_type(8))) short bfrag;   // 8 bf16 (4 VGPR)
typedef __attribute__((ext_vector_type(4))) float ffrag;   // 4 fp32 acc

__device__ __forceinline__ short pk(float x) {
    union { bf h; short s; } u; u.h = __float2bfloat16(x); return u.s;
}
__device__ __forceinline__ float b2f_s(short x) {
    union { short s; bf h; } u; u.s = x; return __bfloat162float(u.h);
}

typedef __attribute__((address_space(1))) const void gv_t;
typedef __attribute__((address_space(3))) void lv_t;

// ---------------------------------------------------------------------------
__global__ void detect_int_k(const unsigned int* __restrict__ at, int* flags) {
    __shared__ int ok;
    if (threadIdx.x == 0) ok = 1;
    __syncthreads();
    if (at[2 * threadIdx.x + 1] != 0u) ok = 0;   // benign race
    __syncthreads();
    if (threadIdx.x == 0) flags[0] = ok;
}

__global__ void signal_k(float* out, int n, float val) {
    int i = blockIdx.x * 256 + threadIdx.x;
    if (i < n) out[i] = val;
}

// ---------------------------------------------------------------------------
// Combined weight prep (9 segments in ONE dispatch): fp32 [L][K][N] ->
// bf16 [L][N][K] at wt+dstOff.
// ---------------------------------------------------------------------------
struct TArgs {
    const float* src[9];
    long dstOff[9];
    int K[9], N[9], L[9];
    int blk0[10];
};
__global__ void transp_all(TArgs a, bf* __restrict__ wt) {
    int bid = blockIdx.x;
    int s = 0;
    while (s < 8 && bid >= a.blk0[s + 1]) ++s;
    long idx = (long)(bid - a.blk0[s]) * 256 + threadIdx.x;
    int KN = a.K[s] * a.N[s];
    long sz = (long)KN * a.L[s];
    if (idx >= sz) return;
    int l = (int)(idx / KN);
    int rem = (int)(idx % KN);
    int k = rem / a.N[s], n = rem % a.N[s];
    wt[a.dstOff[s] + (long)l * KN + (long)n * a.K[s] + k] =
        __float2bfloat16(a.src[s][idx]);
}

// ---------------------------------------------------------------------------
// prep_gewtab: prep_gew + prep_etab merged via block-range switch (R11).
// ---------------------------------------------------------------------------
#define ETAB_ELEMS (GG * 24 * 24 * 64)   // 9437184
__global__ void prep_gewtab(const float* __restrict__ geW, short* __restrict__ wh,
                            short* __restrict__ wl, const float* __restrict__ frac,
                            short* __restrict__ eh, short* __restrict__ el) {
    int bid = blockIdx.x;
    if (bid < 192) {
        int idx = bid * 256 + threadIdx.x;   // 3*2*128*64 = 49152
        if (idx >= 49152) return;
        int k = idx & 63;
        int n = (idx >> 6) & 127;
        int half = (idx >> 13) & 1;
        int l = idx >> 14;
        float v = (k < 60) ? geW[(long)l * 69 * 256 + (long)k * 256 + half * 128 + n] : 0.f;
        short hi = pk(v);
        short lo = pk(v - b2f_s(hi));
        wh[idx] = hi;
        wl[idx] = lo;
    } else {
        int idx = (bid - 192) * 256 + threadIdx.x;
        if (idx >= ETAB_ELEMS) return;
        int k = idx & 63;
        int rem = idx >> 6;           // (g*24 + j)*24 + i
        int i = rem % 24;
        int rem2 = rem / 24;
        int j = rem2 % 24;
        int g = rem2 / 24;
        float val = 0.f;
        if (k < 60) {
            int r = (k < 30) ? k : k - 30;
            int d = r / 10, f = r % 10;
            float fd = frac[g * 72 + j * 3 + d] - frac[g * 72 + i * 3 + d];
            fd -= floorf(fd);
            float ang = 6.283185307179586f * (float)f * fd;
            val = (k < 30) ? sinf(ang) : cosf(ang);
        }
        short hi = pk(val);
        eh[idx] = hi;
        el[idx] = pk(val - b2f_s(hi));
    }
}

// ---------------------------------------------------------------------------
// A = [type_emb[atom_types] | time_emb]  (N x 512, fp32)
// ---------------------------------------------------------------------------
__global__ void build_A(const float* __restrict__ t, const float* __restrict__ type_emb,
                        const unsigned int* __restrict__ atoms,
                        float* __restrict__ A, const int* __restrict__ flags) {
    int i64 = flags[0];
    int idx = blockIdx.x * 256 + threadIdx.x;
    if (idx >= NN * 512) return;
    int n = idx >> 9;
    int k = idx & 511;
    if (k < 256) {
        int a = i64 ? (int)atoms[2 * n] : (int)atoms[n];
        A[idx] = type_emb[(long)a * CC + k];
    } else {
        int d = k - 256;
        int g = n / NP;
        float tv = t[g];
        int dd = (d < 128) ? d : d - 128;
        float tf = expf(dd * (-9.210340371976184f / 127.0f));
        float ang = tv * tf;
        A[idx] = (d < 128) ? sinf(ang) : cosf(ang);
    }
}

// ---------------------------------------------------------------------------
// MFMA bf16 GEMM — R11 DMA double-buffered (validated). Used by x0/AI/AO/head.
// ---------------------------------------------------------------------------
__global__ __launch_bounds__(256) void gemm_mfma(
        const float* __restrict__ A, const bf* __restrict__ Wt,
        const float* __restrict__ bias, const float* __restrict__ bias2,
        const float* __restrict__ res,
        float* __restrict__ C, int M, int K, int N, int act) {
    __shared__ __align__(16) short As[2][32 * 72];      // 9.2 KB
    __shared__ __align__(16) short Bs[2][2][64 * 32];   // 16 KB
    int tid = threadIdx.x;
    int lane = tid & 63, w = tid >> 6;
    int wm = w & 1, wn = w >> 1;
    int m0 = blockIdx.x * 32, n0 = blockIdx.y * 64;
    ffrag acc[2] = {};   // [nt]
    int sa_m = tid >> 3, sa_k = (tid & 7) << 3;   // 32 rows x 8 floats
    int fr_row = lane & 15, quad = lane >> 4, fr_k = quad << 3;
    int brow = w * 16 + (lane >> 2);              // 4 waves x 16 rows
    int bko = (lane & 3) << 3;                    // 4 lanes x 8 shorts per row
    const short* wsrc = (const short*)Wt + (long)(n0 + brow) * K + bko;

    // prologue: stage tile 0
    {
        const float* Ap = A + (long)(m0 + sa_m) * K + sa_k;
        float4 a1 = *(const float4*)Ap;
        float4 a2 = *(const float4*)(Ap + 4);
        __builtin_amdgcn_global_load_lds((gv_t*)(wsrc), (lv_t*)(&Bs[0][0][w * 512]), 16, 0, 0);
        __builtin_amdgcn_global_load_lds((gv_t*)(wsrc + 32), (lv_t*)(&Bs[0][1][w * 512]), 16, 0, 0);
        short* ap = &As[0][sa_m * 72 + sa_k];
        ap[0] = pk(a1.x); ap[1] = pk(a1.y); ap[2] = pk(a1.z); ap[3] = pk(a1.w);
        ap[4] = pk(a2.x); ap[5] = pk(a2.y); ap[6] = pk(a2.z); ap[7] = pk(a2.w);
    }
    __syncthreads();   // As[0] visible, B(0) DMA drained

    int nk = K >> 6;
    int cur = 0;
    for (int i = 0; i < nk; ++i) {
        float4 a1n, a2n;
        bool more = (i + 1) < nk;
        if (more) {
            int kn = (i + 1) << 6;
            __builtin_amdgcn_global_load_lds((gv_t*)(wsrc + kn),
                (lv_t*)(&Bs[cur ^ 1][0][w * 512]), 16, 0, 0);
            __builtin_amdgcn_global_load_lds((gv_t*)(wsrc + kn + 32),
                (lv_t*)(&Bs[cur ^ 1][1][w * 512]), 16, 0, 0);
            const float* Ap = A + (long)(m0 + sa_m) * K + kn + sa_k;
            a1n = *(const float4*)Ap;
            a2n = *(const float4*)(Ap + 4);
        }
        bfrag af0  = *(const bfrag*)(&As[cur][(wm * 16 + fr_row) * 72 + fr_k]);
        bfrag af1  = *(const bfrag*)(&As[cur][(wm * 16 + fr_row) * 72 + 32 + fr_k]);
        bfrag bg00 = *(const bfrag*)(&Bs[cur][0][(wn * 32 + fr_row) * 32 + fr_k]);
        bfrag bg01 = *(const bfrag*)(&Bs[cur][0][(wn * 32 + 16 + fr_row) * 32 + fr_k]);
        bfrag bg10 = *(const bfrag*)(&Bs[cur][1][(wn * 32 + fr_row) * 32 + fr_k]);
        bfrag bg11 = *(const bfrag*)(&Bs[cur][1][(wn * 32 + 16 + fr_row) * 32 + fr_k]);
        acc[0] = __builtin_amdgcn_mfma_f32_16x16x32_bf16(af0, bg00, acc[0], 0, 0, 0);
        acc[1] = __builtin_amdgcn_mfma_f32_16x16x32_bf16(af0, bg01, acc[1], 0, 0, 0);
        acc[0] = __builtin_amdgcn_mfma_f32_16x16x32_bf16(af1, bg10, acc[0], 0, 0, 0);
        acc[1] = __builtin_amdgcn_mfma_f32_16x16x32_bf16(af1, bg11, acc[1], 0, 0, 0);
        if (more) {
            short* ap = &As[cur ^ 1][sa_m * 72 + sa_k];
            ap[0] = pk(a1n.x); ap[1] = pk(a1n.y); ap[2] = pk(a1n.z); ap[3] = pk(a1n.w);
            ap[4] = pk(a2n.x); ap[5] = pk(a2n.y); ap[6] = pk(a2n.z); ap[7] = pk(a2n.w);
        }
        __syncthreads();   // buffers reusable; next DMA drained (overlapped MFMA)
        cur ^= 1;
    }

    int mbase = (lane >> 4) << 2;
#pragma unroll
    for (int nt = 0; nt < 2; ++nt) {
        int n = n0 + wn * 32 + nt * 16 + (lane & 15);
        float bv = bias ? ((bias2 && n >= 128) ? bias2[n - 128] : bias[n]) : 0.f;
#pragma unroll
        for (int r = 0; r < 4; ++r) {
            int m = m0 + wm * 16 + mbase + r;
            float v = acc[nt][r] + bv;
            if (act == 1) v = fmaxf(v, 0.f);
            else if (act == 2) v = v / (1.f + expf(-v));
            if (res) v += res[(long)m * N + n];
            C[(long)m * N + n] = v;
        }
    }
}

// ---------------------------------------------------------------------------
// gemm2_fused (R12): fuses the G1->G2 (N1=256) and M1->M2 (N1=512) pairs.
// The intermediate feeds ONLY the second gemm, so stage 1 stores pk(v) into
// an LDS strip instead of fp32->global->pk (fp32 roundtrip is exact => same
// bytes). Bit-exact by construction: identical per-output ascending-k MFMA
// streams (16-row-strip partition changes WHICH wave computes an output,
// never its op sequence — proven R9/R10), and the epilogue text (plain add +
// relu/silu — no fusible mul->add chains) already survived relocation in
// R9/R10/R11. Grid NN/16 = 384 blocks. Removes 6 dispatches + ~113 MB of
// intermediate traffic per forward.
// ---------------------------------------------------------------------------
template<int N1>
__global__ __launch_bounds__(256) void gemm2_fused(
        const float* __restrict__ A, const bf* __restrict__ Wt1,
        const float* __restrict__ bias1, int act1,
        const bf* __restrict__ Wt2, const float* __restrict__ bias2,
        const float* __restrict__ res, float* __restrict__ C) {
    constexpr int PITCH = N1 + 8;
    __shared__ __align__(16) short Astrip[16 * 264];      // A pk'd, K=256
    __shared__ __align__(16) short Strip[16 * PITCH];     // stage-1 out (bf16)
    __shared__ __align__(16) short Bs[2][2][64 * 32];
    int tid = threadIdx.x;
    int lane = tid & 63, w = tid >> 6;
    int m0 = blockIdx.x * 16;
    int fr_row = lane & 15, quad = lane >> 4, fr_k = quad << 3;
    int brow = w * 16 + (lane >> 2);
    int bko = (lane & 3) << 3;
    int mbase = quad << 2;
    int l15 = lane & 15;

    // stage the A strip (16 x 256 fp32 -> pk bf16), pitch 264
    {
        int row = tid >> 4, seg = (tid & 15) << 4;   // 16 floats each
        const float* Ap = A + (long)(m0 + row) * 256 + seg;
        short* dst = &Astrip[row * 264 + seg];
#pragma unroll
        for (int u = 0; u < 16; u += 4) {
            float4 a = *(const float4*)(Ap + u);
            dst[u + 0] = pk(a.x); dst[u + 1] = pk(a.y);
            dst[u + 2] = pk(a.z); dst[u + 3] = pk(a.w);
        }
    }

    // ---- stage 1: Strip = act1(A @ Wt1 + bias1), n-tiles of 64 ----
    for (int t4 = 0; t4 < N1 / 64; ++t4) {
        int n0 = t4 * 64;
        const short* wsrc = (const short*)Wt1 + (long)(n0 + brow) * 256 + bko;
        __builtin_amdgcn_global_load_lds((gv_t*)(wsrc), (lv_t*)(&Bs[0][0][w * 512]), 16, 0, 0);
        __builtin_amdgcn_global_load_lds((gv_t*)(wsrc + 32), (lv_t*)(&Bs[0][1][w * 512]), 16, 0, 0);
        __syncthreads();   // DMA drained; (t4==0) Astrip visible
        ffrag acc = {};
        int cur = 0;
        for (int i = 0; i < 4; ++i) {     // K=256: 4 steps of 64
            bool more = (i + 1) < 4;
            if (more) {
                int kn = (i + 1) << 6;
                __builtin_amdgcn_global_load_lds((gv_t*)(wsrc + kn),
                    (lv_t*)(&Bs[cur ^ 1][0][w * 512]), 16, 0, 0);
                __builtin_amdgcn_global_load_lds((gv_t*)(wsrc + kn + 32),
                    (lv_t*)(&Bs[cur ^ 1][1][w * 512]), 16, 0, 0);
            }
            int k0 = i << 6;
            const short* arow = &Astrip[fr_row * 264 + k0];
            bfrag af0 = *(const bfrag*)(arow + fr_k);
            bfrag af1 = *(const bfrag*)(arow + 32 + fr_k);
            bfrag bg0 = *(const bfrag*)(&Bs[cur][0][(w * 16 + fr_row) * 32 + fr_k]);
            bfrag bg1 = *(const bfrag*)(&Bs[cur][1][(w * 16 + fr_row) * 32 + fr_k]);
            acc = __builtin_amdgcn_mfma_f32_16x16x32_bf16(af0, bg0, acc, 0, 0, 0);
            acc = __builtin_amdgcn_mfma_f32_16x16x32_bf16(af1, bg1, acc, 0, 0, 0);
            __syncthreads();
            cur ^= 1;
        }
        {
            int n = n0 + w * 16 + l15;
            float bv = bias1[n];
#pragma unroll
            for (int r = 0; r < 4; ++r) {
                int ml = mbase + r;
                float v = acc[r] + bv;
                if (act1 == 1) v = fmaxf(v, 0.f);
                else if (act1 == 2) v = v / (1.f + expf(-v));
                Strip[ml * PITCH + n] = pk(v);
            }
        }
    }

    // ---- stage 2: C = Strip @ Wt2 + bias2 + res  (N2=256, K2=N1) ----
    constexpr int NK2 = N1 >> 6;
    for (int t4 = 0; t4 < 4; ++t4) {
        int n0 = t4 * 64;
        const short* wsrc = (const short*)Wt2 + (long)(n0 + brow) * N1 + bko;
        __builtin_amdgcn_global_load_lds((gv_t*)(wsrc), (lv_t*)(&Bs[0][0][w * 512]), 16, 0, 0);
        __builtin_amdgcn_global_load_lds((gv_t*)(wsrc + 32), (lv_t*)(&Bs[0][1][w * 512]), 16, 0, 0);
        __syncthreads();   // DMA drained; (t4==0) fences Strip writes
        ffrag acc = {};
        int cur = 0;
        for (int i = 0; i < NK2; ++i) {
            bool more = (i + 1) < NK2;
            if (more) {
                int kn = (i + 1) << 6;
                __builtin_amdgcn_global_load_lds((gv_t*)(wsrc + kn),
                    (lv_t*)(&Bs[cur ^ 1][0][w * 512]), 16, 0, 0);
                __builtin_amdgcn_global_load_lds((gv_t*)(wsrc + kn + 32),
                    (lv_t*)(&Bs[cur ^ 1][1][w * 512]), 16, 0, 0);
            }
            int k0 = i << 6;
            const short* arow = &Strip[fr_row * PITCH + k0];
            bfrag af0 = *(const bfrag*)(arow + fr_k);
            bfrag af1 = *(const bfrag*)(arow + 32 + fr_k);
            bfrag bg0 = *(const bfrag*)(&Bs[cur][0][(w * 16 + fr_row) * 32 + fr_k]);
            bfrag bg1 = *(const bfrag*)(&Bs[cur][1][(w * 16 + fr_row) * 32 + fr_k]);
            acc = __builtin_amdgcn_mfma_f32_16x16x32_bf16(af0, bg0, acc, 0, 0, 0);
            acc = __builtin_amdgcn_mfma_f32_16x16x32_bf16(af1, bg1, acc, 0, 0, 0);
            __syncthreads();
            cur ^= 1;
        }
        {
            int n = n0 + w * 16 + l15;
            float bv = bias2[n];
#pragma unroll
            for (int r = 0; r < 4; ++r) {
                int m = m0 + mbase + r;
                float v = acc[r] + bv;
                v += res[(long)m * 256 + n];
                C[(long)m * 256 + n] = v;
            }
        }
    }
}

// ---------------------------------------------------------------------------
// fp32 tiled GEMM (small/odd-N) with lda (validated R11).
// ---------------------------------------------------------------------------
__global__ __launch_bounds__(256) void gemm_k(
        const float* __restrict__ A, int lda, const float* __restrict__ W,
        const float* __restrict__ bias, const float* __restrict__ res,
        float* __restrict__ Cf, int M, int K, int Nc, int act) {
    __shared__ __align__(16) float Asf[32][64];
    __shared__ __align__(16) float Bsf[32][64];
    int tid = threadIdx.x;
    int tx = tid & 15, ty = tid >> 4;
    int m0 = blockIdx.x * 64, n0 = blockIdx.y * 64;
    float acc[4][4] = {{0.f}};
    int am = tid >> 2;
    int ak = (tid & 3) << 3;
    int bk = tid >> 4;
    int bn = (tid & 15) << 2;

    for (int k0 = 0; k0 < K; k0 += 32) {
        const float* Ap = A + (long)(m0 + am) * lda + k0 + ak;
        float4 a1 = *(const float4*)Ap;
        float4 a2 = *(const float4*)(Ap + 4);
        float w1[4], w2[4];
#pragma unroll
        for (int u = 0; u < 4; ++u) {
            int n = n0 + bn + u;
            w1[u] = (n < Nc) ? W[(long)(k0 + bk) * Nc + n] : 0.f;
            w2[u] = (n < Nc) ? W[(long)(k0 + bk + 16) * Nc + n] : 0.f;
        }
        __syncthreads();
        Asf[ak + 0][am] = a1.x; Asf[ak + 1][am] = a1.y;
        Asf[ak + 2][am] = a1.z; Asf[ak + 3][am] = a1.w;
        Asf[ak + 4][am] = a2.x; Asf[ak + 5][am] = a2.y;
        Asf[ak + 6][am] = a2.z; Asf[ak + 7][am] = a2.w;
#pragma unroll
        for (int u = 0; u < 4; ++u) {
            Bsf[bk][bn + u] = w1[u];
            Bsf[bk + 16][bn + u] = w2[u];
        }
        __syncthreads();
#pragma unroll
        for (int k = 0; k < 32; ++k) {
            float4 a = *(const float4*)(&Asf[k][ty << 2]);
            float4 b = *(const float4*)(&Bsf[k][tx << 2]);
            acc[0][0] += a.x * b.x; acc[0][1] += a.x * b.y; acc[0][2] += a.x * b.z; acc[0][3] += a.x * b.w;
            acc[1][0] += a.y * b.x; acc[1][1] += a.y * b.y; acc[1][2] += a.y * b.z; acc[1][3] += a.y * b.w;
            acc[2][0] += a.z * b.x; acc[2][1] += a.z * b.y; acc[2][2] += a.z * b.z; acc[2][3] += a.z * b.w;
            acc[3][0] += a.w * b.x; acc[3][1] += a.w * b.y; acc[3][2] += a.w * b.z; acc[3][3] += a.w * b.w;
        }
    }
#pragma unroll
    for (int i = 0; i < 4; ++i) {
        int m = m0 + (ty << 2) + i;
#pragma unroll
        for (int j = 0; j < 4; ++j) {
            int n = n0 + (tx << 2) + j;
            if (n >= Nc) continue;
            float v = acc[i][j];
            if (bias) v += bias[n];
            if (act == 1) v = fmaxf(v, 0.f);
            else if (act == 2) v = v / (1.f + expf(-v));
            if (res) v += res[(long)m * Nc + n];
            Cf[(long)m * Nc + n] = v;
        }
    }
}

// ---------------------------------------------------------------------------
// GINE v13 — R1/R4 structure + async DMA double-buffered E staging.
// WIN R6: 957 -> 890 µs. Unchanged since.
// ---------------------------------------------------------------------------
#define MF(a, b, c) c = __builtin_amdgcn_mfma_f32_16x16x32_bf16(a, b, c, 0, 0, 0)

// Stage one 24x64-short E-tile pair (eh->lds[0..1535], el->lds[2048..3583])
// as 6 DMA chunks of 512 shorts (64 lanes x 16 B). Wave w: chunks w, w+4.
__device__ __forceinline__ void stage_etile(const short* __restrict__ ej_h,
                                            const short* __restrict__ ej_l,
                                            short* lds_base, int w, int lane) {
    {
        int c = w;   // 0..3
        const short* src = (c < 3) ? (ej_h + c * 512) : (ej_l + (c - 3) * 512);
        int doff = (c < 3) ? c * 512 : 2048 + (c - 3) * 512;
        __builtin_amdgcn_global_load_lds((gv_t*)(src + lane * 8),
                                         (lv_t*)(lds_base + doff), 16, 0, 0);
    }
    if (w < 2) {
        int c = w + 4;   // 4,5 -> el chunks 1,2
        const short* src = ej_l + (c - 3) * 512;
        int doff = 2048 + (c - 3) * 512;
        __builtin_amdgcn_global_load_lds((gv_t*)(src + lane * 8),
                                         (lv_t*)(lds_base + doff), 16, 0, 0);
    }
}

__global__ __launch_bounds__(256, 4) void gine4(
        const float* __restrict__ x,
        const float* __restrict__ lattice, const float* __restrict__ geW,
        const float* __restrict__ geb, const short* __restrict__ gewt_h,
        const short* __restrict__ gewt_l, const short* __restrict__ et_h,
        const short* __restrict__ et_l, float* __restrict__ z, int l) {
    __shared__ __align__(16) float xls[24 * 132];  // 12672 B
    __shared__ float basel[128];                   // 512 B
    __shared__ __align__(16) short ebuf[8192];     // 2 x (eh 32r + el 32r) x 64

    int tid = threadIdx.x;
    int lane = tid & 63, w = tid >> 6, quad = lane >> 4, l16 = lane & 15;
    int g = blockIdx.x >> 2;
    int half = (blockIdx.x >> 1) & 1;
    int jh = blockIdx.x & 1;           // j range jh*12 .. jh*12+11

    // ---- stage x half (float4), base ----
    {
        const float4* xg = (const float4*)x;
        for (int idx = tid; idx < 768; idx += 256) {
            int i = idx >> 5, c4 = idx & 31;
            ((float4*)(xls + i * 132))[c4] =
                xg[((long)(g * NP + i) * CC + half * 128) / 4 + c4];
        }
    }
    if (tid < 128) {
        int cg = half * 128 + tid;
        float bv = geb[(long)l * CC + cg];
#pragma unroll
        for (int q = 0; q < 9; ++q)
            bv += lattice[(long)g * 9 + q] * geW[(long)l * 69 * 256 + (long)(60 + q) * 256 + cg];
        basel[tid] = bv;
    }

    // ---- B fragments direct from global (loop-invariant, named scalars) ----
    bfrag bh00, bh01, bh10, bh11, bl00, bl01, bl10, bl11;
    {
        long base = (long)(l * 2 + half) * 8192;   // shorts: 128 rows x 64
        int nrow0 = w * 32 + l16;                  // nt=0
        int nrow1 = w * 32 + 16 + l16;             // nt=1
        const short* p0h = gewt_h + base + nrow0 * 64 + quad * 8;
        const short* p1h = gewt_h + base + nrow1 * 64 + quad * 8;
        const short* p0l = gewt_l + base + nrow0 * 64 + quad * 8;
        const short* p1l = gewt_l + base + nrow1 * 64 + quad * 8;
        bh00 = *(const bfrag*)(p0h);      bh01 = *(const bfrag*)(p0h + 32);
        bh10 = *(const bfrag*)(p1h);      bh11 = *(const bfrag*)(p1h + 32);
        bl00 = *(const bfrag*)(p0l);      bl01 = *(const bfrag*)(p0l + 32);
        bl10 = *(const bfrag*)(p1l);      bl11 = *(const bfrag*)(p1l + 32);
    }

    const short* ehg = et_h + (long)g * (24 * 24 * 64);
    const short* elg = et_l + (long)g * (24 * 24 * 64);
    int j0 = jh * 12;

    // prologue: DMA first tile into buf 0
    stage_etile(ehg + (long)j0 * 1536, elg + (long)j0 * 1536, ebuf, w, lane);
    __syncthreads();   // drains DMA + makes xls/basel visible

    float bse0 = basel[w * 32 + l16];
    float bse1 = basel[w * 32 + 16 + l16];

    int cur = 0;
    for (int jc = 0; jc < 12; ++jc) {
        int j = j0 + jc;
        // issue next tile's DMA into the other buffer (hidden under compute)
        if (jc < 11) {
            stage_etile(ehg + (long)(j + 1) * 1536, elg + (long)(j + 1) * 1536,
                        ebuf + (cur ^ 1) * 4096, w, lane);
        }

        const short* eb = ebuf + cur * 4096;
        int r0 = l16 * 64 + quad * 8;          // mt=0 row offset (shorts)
        int r1 = (16 + l16) * 64 + quad * 8;   // mt=1
        bfrag ah00 = *(const bfrag*)(eb + r0);
        bfrag ah01 = *(const bfrag*)(eb + r0 + 32);
        bfrag ah10 = *(const bfrag*)(eb + r1);
        bfrag ah11 = *(const bfrag*)(eb + r1 + 32);
        bfrag al00 = *(const bfrag*)(eb + 2048 + r0);
        bfrag al01 = *(const bfrag*)(eb + 2048 + r0 + 32);
        bfrag al10 = *(const bfrag*)(eb + 2048 + r1);
        bfrag al11 = *(const bfrag*)(eb + 2048 + r1 + 32);

        ffrag a00 = {}, a01 = {}, a10 = {}, a11 = {};   // acc[mt][nt]
        // mt=0, ks=0
        MF(ah00, bh00, a00); MF(ah00, bl00, a00); MF(al00, bh00, a00);
        MF(ah00, bh10, a01); MF(ah00, bl10, a01); MF(al00, bh10, a01);
        // mt=0, ks=1
        MF(ah01, bh01, a00); MF(ah01, bl01, a00); MF(al01, bh01, a00);
        MF(ah01, bh11, a01); MF(ah01, bl11, a01); MF(al01, bh11, a01);
        // mt=1, ks=0
        MF(ah10, bh00, a10); MF(ah10, bl00, a10); MF(al10, bh00, a10);
        MF(ah10, bh10, a11); MF(ah10, bl10, a11); MF(al10, bh10, a11);
        // mt=1, ks=1
        MF(ah11, bh01, a10); MF(ah11, bl01, a10); MF(al11, bh01, a10);
        MF(ah11, bh11, a11); MF(ah11, bl11, a11); MF(al11, bh11, a11);

        // epilogue: relu + reduce over i, write z[g*24+j][cg]
#pragma unroll
        for (int nt = 0; nt < 2; ++nt) {
            int cl = w * 32 + nt * 16 + l16;
            float bse = nt ? bse1 : bse0;
            ffrag am0 = nt ? a01 : a00;   // mt=0 acc (ibase = quad*4, < 24)
            ffrag am1 = nt ? a11 : a10;   // mt=1 acc (valid only quad<2)
            float part = 0.f;
            {
                int ibase = quad * 4;
#pragma unroll
                for (int r = 0; r < 4; ++r) {
                    float xv = xls[(ibase + r) * 132 + cl];
                    part += fmaxf(xv + bse + am0[r], 0.f);
                }
            }
            if (quad < 2) {
                int ibase = 16 + quad * 4;
#pragma unroll
                for (int r = 0; r < 4; ++r) {
                    float xv = xls[(ibase + r) * 132 + cl];
                    part += fmaxf(xv + bse + am1[r], 0.f);
                }
            }
            part += __shfl_xor(part, 16);
            part += __shfl_xor(part, 32);
            if (lane < 16)
                z[(long)(g * NP + j) * CC + half * 128 + cl] = xls[j * 132 + cl] + part;
        }
        __syncthreads();
        cur ^= 1;
    }
}

// ---------------------------------------------------------------------------
// BN: R7-exact structure (contraction-sensitive expressions pinned to their
// original kernels — R8's relocation attempt shifted absmax one quantum).
// ---------------------------------------------------------------------------
__global__ void bn_stats1(const float* __restrict__ in, float* __restrict__ part) {
    int c = threadIdx.x, b = blockIdx.x;
    float s = 0.f, q = 0.f;
    for (int r = 0; r < 64; ++r) {
        float v = in[(long)(b * 64 + r) * CC + c];
        s += v; q += v * v;
    }
    part[b * 512 + c] = s;
    part[b * 512 + 256 + c] = q;
}
__global__ __launch_bounds__(256) void bn_apply2(
        const float* __restrict__ in, const float* __restrict__ part,
        const float* __restrict__ gma, const float* __restrict__ bta,
        const float* __restrict__ add, float* __restrict__ out) {
    int c = threadIdx.x;
    float s = 0.f, q = 0.f;
    for (int b = 0; b < 96; ++b) { s += part[b * 512 + c]; q += part[b * 512 + 256 + c]; }
    float m = s / (float)NN;
    float var = q / (float)NN - m * m;
    float stats_c = m;
    float stats_rs = rsqrtf(var + 1e-5f);
    float gc = gma[c], bc = bta[c];
    for (int r = blockIdx.x; r < NN; r += 768) {
        long idx = (long)r * CC + c;
        float v = (in[idx] - stats_c) * stats_rs * gc + bc;
        if (add) v += add[idx];
        out[idx] = v;
    }
}

// ---------------------------------------------------------------------------
// Attention v2 (validated R10).
// ---------------------------------------------------------------------------
__global__ __launch_bounds__(256, 2) void attn2(const float* __restrict__ qkv,
                                                float* __restrict__ o) {
    __shared__ __align__(16) float Kl[24 * 4 * 68];
    __shared__ __align__(16) float Vl[24 * 4 * 68];
    __shared__ float S[4 * 24 * 25];
    int tid = threadIdx.x, g = blockIdx.x;

    const float4* qkv4 = (const float4*)(qkv + (long)g * NP * 768);
    for (int idx = tid; idx < 24 * 128; idx += 256) {
        int row = idx >> 7;
        int c4 = idx & 127;
        int isV = c4 >> 6;
        int cc = c4 & 63;
        int h = cc >> 4, d4 = cc & 15;
        float4 val = qkv4[row * 192 + 64 + c4];
        float* dst = (isV ? Vl : Kl) + (row * 4 + h) * 68 + d4 * 4;
        *(float4*)dst = val;
    }
    __syncthreads();

    if (tid < 96) {
        int h = tid & 3, i = tid >> 2;
        const float4* qp = (const float4*)(qkv + ((long)(g * NP + i)) * 768 + h * 64);
        float4 q[16];
#pragma unroll
        for (int k = 0; k < 16; ++k) q[k] = qp[k];
        float sc[24];
        float mx = -1e30f;
        for (int j = 0; j < 24; ++j) {
            const float4* kp = (const float4*)(Kl + (j * 4 + h) * 68);
            float da = 0.f, db = 0.f;
#pragma unroll
            for (int k = 0; k < 16; k += 2) {
                float4 kv = kp[k];
                da += q[k].x * kv.x; da += q[k].y * kv.y;
                da += q[k].z * kv.z; da += q[k].w * kv.w;
                float4 kv2 = kp[k + 1];
                db += q[k + 1].x * kv2.x; db += q[k + 1].y * kv2.y;
                db += q[k + 1].z * kv2.z; db += q[k + 1].w * kv2.w;
            }
            float s = (da + db) * 0.125f;
            sc[j] = s;
            mx = fmaxf(mx, s);
        }
        float sum = 0.f;
#pragma unroll
        for (int j = 0; j < 24; ++j) { float p = expf(sc[j] - mx); sc[j] = p; sum += p; }
        float inv = 1.f / sum;
#pragma unroll
        for (int j = 0; j < 24; ++j) S[(h * 24 + i) * 25 + j] = sc[j] * inv;
    }
    __syncthreads();

    int h = tid >> 6, d = tid & 63;
    for (int i = 0; i < 24; ++i) {
        const float* Sp = S + (h * 24 + i) * 25;
        float a0 = 0.f, a1 = 0.f;
#pragma unroll
        for (int j = 0; j < 24; j += 2) {
            a0 += Sp[j] * Vl[(j * 4 + h) * 68 + d];
            a1 += Sp[j + 1] * Vl[((j + 1) * 4 + h) * 68 + d];
        }
        o[(long)(g * NP + i) * CC + h * 64 + d] = a0 + a1;
    }
}

// ---------------------------------------------------------------------------
__global__ __launch_bounds__(256) void ln_kernel(const float* __restrict__ x,
        const float* __restrict__ gma, const float* __restrict__ bta,
        float* __restrict__ out) {
    __shared__ float red[256];
    int n = blockIdx.x, c = threadIdx.x;
    float v = x[(long)n * CC + c];
    red[c] = v;
    __syncthreads();
    for (int s = 128; s > 0; s >>= 1) { if (c < s) red[c] += red[c + s]; __syncthreads(); }
    float m = red[0] * (1.f / 256.f);
    __syncthreads();
    float dv = v - m;
    red[c] = dv * dv;
    __syncthreads();
    for (int s = 128; s > 0; s >>= 1) { if (c < s) red[c] += red[c + s]; __syncthreads(); }
    float var = red[0] * (1.f / 256.f);
    out[(long)n * CC + c] = dv * rsqrtf(var + 1e-5f) * gma[c] + bta[c];
}

// ---------------------------------------------------------------------------
// Fused lattice head (R11: pool folded in; validated).
// ---------------------------------------------------------------------------
__global__ __launch_bounds__(256) void lat_head(
        const float* __restrict__ hn, const float* __restrict__ W1,
        const float* __restrict__ b1, const float* __restrict__ W2,
        const float* __restrict__ b2, const float* __restrict__ W3,
        float* __restrict__ out) {
    __shared__ float gfl[256];
    __shared__ float h1[128];
    __shared__ float h2[64];
    int g = blockIdx.x, t = threadIdx.x;
    {
        float s = 0.f;
        for (int j = 0; j < NP; ++j) s += hn[(long)(g * NP + j) * CC + t];
        gfl[t] = s * (1.f / 24.f);
    }
    __syncthreads();
    if (t < 128) {
        float acc = 0.f;
        for (int k = 0; k < 256; ++k) acc += gfl[k] * W1[k * 128 + t];
        float v = acc;
        v += b1[t];
        v = v / (1.f + expf(-v));
        h1[t] = v;
    }
    __syncthreads();
    if (t < 64) {
        float acc = 0.f;
        for (int k = 0; k < 128; ++k) acc += h1[k] * W2[k * 64 + t];
        float v = acc;
        v += b2[t];
        v = v / (1.f + expf(-v));
        h2[t] = v;
    }
    __syncthreads();
    if (t < 9) {
        float acc = 0.f;
        for (int k = 0; k < 64; ++k) acc += h2[k] * W3[k * 9 + t];
        out[(long)g * 9 + t] = acc;
    }
}

// ---------------------------------------------------------------------------
static void gemm(hipStream_t st, const float* A, int lda, const float* W,
                 const float* bias, const float* res, float* Cf,
                 int M, int K, int Nc, int act) {
    dim3 grid(M / 64, (Nc + 63) / 64);
    gemm_k<<<grid, 256, 0, st>>>(A, lda, W, bias, res, Cf, M, K, Nc, act);
}

static void gemmM(hipStream_t st, const float* A, const bf* Wt, const float* bias,
                  const float* bias2, const float* res, float* Cf,
                  int M, int K, int N, int act) {
    dim3 grid(M / 32, N / 64);
    gemm_mfma<<<grid, 256, 0, st>>>(A, Wt, bias, bias2, res, Cf, M, K, N, act);
}

static void run_bn(hipStream_t st, const float* in, float* part,
                   const float* g_, const float* b_, const float* add, float* out) {
    bn_stats1<<<96, 256, 0, st>>>(in, part);
    bn_apply2<<<768, 256, 0, st>>>(in, part, g_, b_, add, out);
}

extern "C" void kernel_launch(void* const* d_in, const int* in_sizes, int n_in,
                              void* d_out, int out_size, void* d_ws, size_t ws_size,
                              hipStream_t stream) {
    float* out = (float*)d_out;
    int sigN = out_size < 256 ? out_size : 256;

    static const int EXP_SIZES[46] = {
        256, 18432, 2304, 25600, 131072, 256, 52992, 768, 196608, 768,
        196608, 768, 589824, 2304, 196608, 768, 393216, 1536, 393216, 768,
        768, 768, 768, 768, 768, 768, 256, 256, 32768, 128,
        12800, 100, 32768, 128, 8192, 64, 576, 32768, 128, 8192,
        64, 192, 6144, 6144, 147456, 147456 };
    if (n_in != 46) { signal_k<<<1, 256, 0, stream>>>(out, sigN, 3000.f + 8.f * n_in); return; }
    for (int i = 0; i < 46; ++i)
        if (in_sizes[i] != EXP_SIZES[i]) { signal_k<<<1, 256, 0, stream>>>(out, sigN, 512.f + 8.f * i); return; }
    if (out_size != NN * 100 + GG * 9 + NN * 3) { signal_k<<<1, 256, 0, stream>>>(out, sigN, 7777.f); return; }

    // ---- workspace (R7-exact layout) ----
    char* base = (char*)d_ws;
    int* flags = (int*)base;                       // 256 B
    float* f32a = (float*)(base + 256);
    float* x  = f32a;                              // N*256
    float* s1 = x  + (size_t)NN * 256;             // N*256
    float* s2 = s1 + (size_t)NN * 256;             // N*256
    float* big = s2 + (size_t)NN * 256;            // N*768
    float* s3 = big + (size_t)NN * 512;            // alias of big's tail (lifetimes audited)
    float* part = big + (size_t)NN * 768;          // 96*512
    float* stats = part + 96 * 512;                // 512 (unused)
    float* gf  = stats + 512;                      // G*256 (unused)
    float* l1b = gf + GG * 256;                    // G*128 (unused)
    float* l2b = l1b + GG * 128;                   // G*64  (unused)
    bf* wt = (bf*)(l2b + GG * 64);                 // bf16 W^T mirrors
    const long O_NA = 0, O_G1 = 131072, O_G2 = 327680, O_AI = 524288,
               O_AO = 1114112, O_M1 = 1310720, O_M2 = 1703936,
               O_TRO = 2097152, O_FC = 2129920, WT_TOT = 2162688;
    short* gewt_h = (short*)(wt + WT_TOT);         // 49152 shorts
    short* gewt_l = gewt_h + 49152;                // 49152 shorts
    short* et_h = gewt_l + 49152;
    short* et_l = et_h + (ETAB_ELEMS + 1024);
    size_t REQ = 256 + ((size_t)NN * 1536 + 96 * 512 + 512 + GG * 448) * 4
               + WT_TOT * 2 + 49152 * 2 * 2
               + ((size_t)ETAB_ELEMS + 1024) * 2 * 2;
    if (ws_size < REQ) { signal_k<<<1, 256, 0, stream>>>(out, sigN, 9999.f); return; }

    const float* t       = (const float*)d_in[0];
    const float* frac    = (const float*)d_in[1];
    const float* lattice = (const float*)d_in[2];
    const float* type_emb = (const float*)d_in[3];

    detect_int_k<<<1, 256, 0, stream>>>((const unsigned int*)d_in[42], flags);

    // combined weight prep (one dispatch for the 9 transposes)
    {
        TArgs ta;
        const int srcIdx[9] = {4, 8, 10, 12, 14, 16, 18, 28, 37};
        const long dof[9]  = {O_NA, O_G1, O_G2, O_AI, O_AO, O_M1, O_M2, O_TRO, O_FC};
        const int Ks[9] = {512, 256, 256, 256, 256, 256, 512, 256, 256};
        const int Ns[9] = {256, 256, 256, 768, 256, 512, 256, 128, 128};
        const int Ls[9] = {1, 3, 3, 3, 3, 3, 3, 1, 1};
        int blk = 0;
        for (int s = 0; s < 9; ++s) {
            ta.src[s] = (const float*)d_in[srcIdx[s]];
            ta.dstOff[s] = dof[s];
            ta.K[s] = Ks[s]; ta.N[s] = Ns[s]; ta.L[s] = Ls[s];
            ta.blk0[s] = blk;
            blk += (Ks[s] * Ns[s] * Ls[s] + 255) / 256;
        }
        ta.blk0[9] = blk;
        transp_all<<<blk, 256, 0, stream>>>(ta, wt);
    }
    prep_gewtab<<<192 + (ETAB_ELEMS + 255) / 256, 256, 0, stream>>>(
        (const float*)d_in[6], gewt_h, gewt_l, frac, et_h, et_l);

    // x0 = concat(type_emb[atoms], time_emb) @ naW + nab
    build_A<<<(NN * 512 + 255) / 256, 256, 0, stream>>>(t, type_emb,
        (const unsigned int*)d_in[42], big, flags);
    gemmM(stream, big, wt + O_NA, (const float*)d_in[5], nullptr, nullptr, x, NN, 512, 256, 0);

    for (int l = 0; l < LL; ++l) {
        // GINE: s1 = x + aggr
        gine4<<<GG * 4, 256, 0, stream>>>(x, lattice,
            (const float*)d_in[6], (const float*)d_in[7], gewt_h, gewt_l,
            et_h, et_l, s1, l);
        // fused G1+G2: s3 = silu(s1@gW1+gb1)@gW2 + gb2 + x; h1 = BN(s3) -> s2
        gemm2_fused<256><<<NN / 16, 256, 0, stream>>>(s1,
            wt + O_G1 + (long)l * 65536, (const float*)d_in[9] + l * 256, 2,
            wt + O_G2 + (long)l * 65536, (const float*)d_in[11] + l * 256, x, s3);
        run_bn(stream, s3, part, (const float*)d_in[20] + l * 256, (const float*)d_in[21] + l * 256, nullptr, s2);
        // attention: qkv=big; o=s1; s3 = s1@aoW+aob + x; s1 = h1 + BN(s3)
        gemmM(stream, x, wt + O_AI + (long)l * 196608, (const float*)d_in[13] + l * 768, nullptr, nullptr, big, NN, 256, 768, 0);
        attn2<<<GG, 256, 0, stream>>>(big, s1);
        gemmM(stream, s1, wt + O_AO + (long)l * 65536, (const float*)d_in[15] + l * 256, nullptr, x, s3, NN, 256, 256, 0);
        run_bn(stream, s3, part, (const float*)d_in[22] + l * 256, (const float*)d_in[23] + l * 256, s2, s1);
        // fused M1+M2: s3 = relu(s1@mW1+mb1)@mW2 + mb2 + s1; x = BN(s3)
        gemm2_fused<512><<<NN / 16, 256, 0, stream>>>(s1,
            wt + O_M1 + (long)l * 131072, (const float*)d_in[17] + l * 512, 1,
            wt + O_M2 + (long)l * 131072, (const float*)d_in[19] + l * 256, s1, s3);
        run_bn(stream, s3, part, (const float*)d_in[24] + l * 256, (const float*)d_in[25] + l * 256, nullptr, x);
    }

    ln_kernel<<<NN, 256, 0, stream>>>(x, (const float*)d_in[26], (const float*)d_in[27], s1);

    // heads: combined TRO|FC gemm (adjacent mirrors, concat bias) -> s2 [NN x 256]
    gemmM(stream, s1, wt + O_TRO, (const float*)d_in[29], (const float*)d_in[38],
          nullptr, s2, NN, 256, 256, 2);
    // types_pred -> out[0 : N*100]   (A = s2 cols 0..127, lda=256)
    gemm(stream, s2, 256, (const float*)d_in[30], (const float*)d_in[31], nullptr, out, NN, 128, 100, 0);
    // lattice_pred -> out[N*100 : +G*9]  (pool folded into lat_head)
    lat_head<<<GG, 256, 0, stream>>>(s1, (const float*)d_in[32], (const float*)d_in[33],
        (const float*)d_in[34], (const float*)d_in[35], (const float*)d_in[36],
        out + (size_t)NN * 100);
    // frac_pred -> out[N*100+G*9 : ]  (A = s2 cols 128..255)
    gemm(stream, s2 + 128, 256, (const float*)d_in[39], (const float*)d_in[40], nullptr, s3, NN, 128, 64, 2);
    gemm(stream, s3, 64, (const float*)d_in[41], nullptr, nullptr, out + (size_t)NN * 100 + GG * 9, NN, 64, 3, 0);
}

// Round 13
// 708.523 us; speedup vs baseline: 1.0704x; 1.0704x over previous
//
#include <hip/hip_runtime.h>
#include <hip/hip_bf16.h>
#include <math.h>

#define GG 256
#define NP 24
#define LL 3
#define CC 256
#define NN (GG*NP)   // 6144 nodes
#define HH 4
#define DH 64

typedef __hip_bfloat16 bf;
typedef __attribute__((ext_vector_type(8))) short bfrag;   // 8 bf16 (4 VGPR)
typedef __attribute__((ext_vector_type(4))) float ffrag;   // 4 fp32 acc

__device__ __forceinline__ short pk(float x) {
    union { bf h; short s; } u; u.h = __float2bfloat16(x); return u.s;
}
__device__ __forceinline__ float b2f_s(short x) {
    union { short s; bf h; } u; u.s = x; return __bfloat162float(u.h);
}

typedef __attribute__((address_space(1))) const void gv_t;
typedef __attribute__((address_space(3))) void lv_t;

// ---------------------------------------------------------------------------
__global__ void signal_k(float* out, int n, float val) {
    int i = blockIdx.x * 256 + threadIdx.x;
    if (i < n) out[i] = val;
}

// ---------------------------------------------------------------------------
// Combined weight prep (9 segments in ONE dispatch): fp32 [L][K][N] ->
// bf16 [L][N][K] at wt+dstOff.
// ---------------------------------------------------------------------------
struct TArgs {
    const float* src[9];
    long dstOff[9];
    int K[9], N[9], L[9];
    int blk0[10];
};
__global__ void transp_all(TArgs a, bf* __restrict__ wt) {
    int bid = blockIdx.x;
    int s = 0;
    while (s < 8 && bid >= a.blk0[s + 1]) ++s;
    long idx = (long)(bid - a.blk0[s]) * 256 + threadIdx.x;
    int KN = a.K[s] * a.N[s];
    long sz = (long)KN * a.L[s];
    if (idx >= sz) return;
    int l = (int)(idx / KN);
    int rem = (int)(idx % KN);
    int k = rem / a.N[s], n = rem % a.N[s];
    wt[a.dstOff[s] + (long)l * KN + (long)n * a.K[s] + k] =
        __float2bfloat16(a.src[s][idx]);
}

// ---------------------------------------------------------------------------
// prep_gewtab: prep_gew + prep_etab merged via block-range switch (R11).
// ---------------------------------------------------------------------------
#define ETAB_ELEMS (GG * 24 * 24 * 64)   // 9437184
__global__ void prep_gewtab(const float* __restrict__ geW, short* __restrict__ wh,
                            short* __restrict__ wl, const float* __restrict__ frac,
                            short* __restrict__ eh, short* __restrict__ el) {
    int bid = blockIdx.x;
    if (bid < 192) {
        int idx = bid * 256 + threadIdx.x;   // 3*2*128*64 = 49152
        if (idx >= 49152) return;
        int k = idx & 63;
        int n = (idx >> 6) & 127;
        int half = (idx >> 13) & 1;
        int l = idx >> 14;
        float v = (k < 60) ? geW[(long)l * 69 * 256 + (long)k * 256 + half * 128 + n] : 0.f;
        short hi = pk(v);
        short lo = pk(v - b2f_s(hi));
        wh[idx] = hi;
        wl[idx] = lo;
    } else {
        int idx = (bid - 192) * 256 + threadIdx.x;
        if (idx >= ETAB_ELEMS) return;
        int k = idx & 63;
        int rem = idx >> 6;           // (g*24 + j)*24 + i
        int i = rem % 24;
        int rem2 = rem / 24;
        int j = rem2 % 24;
        int g = rem2 / 24;
        float val = 0.f;
        if (k < 60) {
            int r = (k < 30) ? k : k - 30;
            int d = r / 10, f = r % 10;
            float fd = frac[g * 72 + j * 3 + d] - frac[g * 72 + i * 3 + d];
            fd -= floorf(fd);
            float ang = 6.283185307179586f * (float)f * fd;
            val = (k < 30) ? sinf(ang) : cosf(ang);
        }
        short hi = pk(val);
        eh[idx] = hi;
        el[idx] = pk(val - b2f_s(hi));
    }
}

// ---------------------------------------------------------------------------
// A = [type_emb[atom_types] | time_emb]  (N x 512, fp32).
// R13: int64-detection folded in (verbatim shared-flag pattern per block;
// the decision is a deterministic predicate of the input bytes — only the
// integer index-select path depends on it). Removes the detect_int_k
// dispatch and the flags dependency.
// ---------------------------------------------------------------------------
__global__ void build_A(const float* __restrict__ t, const float* __restrict__ type_emb,
                        const unsigned int* __restrict__ atoms,
                        float* __restrict__ A) {
    __shared__ int ok;
    if (threadIdx.x == 0) ok = 1;
    __syncthreads();
    if (atoms[2 * threadIdx.x + 1] != 0u) ok = 0;   // benign race
    __syncthreads();
    int i64 = ok;
    int idx = blockIdx.x * 256 + threadIdx.x;
    if (idx >= NN * 512) return;
    int n = idx >> 9;
    int k = idx & 511;
    if (k < 256) {
        int a = i64 ? (int)atoms[2 * n] : (int)atoms[n];
        A[idx] = type_emb[(long)a * CC + k];
    } else {
        int d = k - 256;
        int g = n / NP;
        float tv = t[g];
        int dd = (d < 128) ? d : d - 128;
        float tf = expf(dd * (-9.210340371976184f / 127.0f));
        float ang = tv * tf;
        A[idx] = (d < 128) ? sinf(ang) : cosf(ang);
    }
}

// ---------------------------------------------------------------------------
// MFMA bf16 GEMM — R11 DMA double-buffered (validated, 712.5 µs config).
// ---------------------------------------------------------------------------
__global__ __launch_bounds__(256) void gemm_mfma(
        const float* __restrict__ A, const bf* __restrict__ Wt,
        const float* __restrict__ bias, const float* __restrict__ bias2,
        const float* __restrict__ res,
        float* __restrict__ C, int M, int K, int N, int act) {
    __shared__ __align__(16) short As[2][32 * 72];      // 9.2 KB
    __shared__ __align__(16) short Bs[2][2][64 * 32];   // 16 KB
    int tid = threadIdx.x;
    int lane = tid & 63, w = tid >> 6;
    int wm = w & 1, wn = w >> 1;
    int m0 = blockIdx.x * 32, n0 = blockIdx.y * 64;
    ffrag acc[2] = {};   // [nt]
    int sa_m = tid >> 3, sa_k = (tid & 7) << 3;   // 32 rows x 8 floats
    int fr_row = lane & 15, quad = lane >> 4, fr_k = quad << 3;
    int brow = w * 16 + (lane >> 2);              // 4 waves x 16 rows
    int bko = (lane & 3) << 3;                    // 4 lanes x 8 shorts per row
    const short* wsrc = (const short*)Wt + (long)(n0 + brow) * K + bko;

    // prologue: stage tile 0
    {
        const float* Ap = A + (long)(m0 + sa_m) * K + sa_k;
        float4 a1 = *(const float4*)Ap;
        float4 a2 = *(const float4*)(Ap + 4);
        __builtin_amdgcn_global_load_lds((gv_t*)(wsrc), (lv_t*)(&Bs[0][0][w * 512]), 16, 0, 0);
        __builtin_amdgcn_global_load_lds((gv_t*)(wsrc + 32), (lv_t*)(&Bs[0][1][w * 512]), 16, 0, 0);
        short* ap = &As[0][sa_m * 72 + sa_k];
        ap[0] = pk(a1.x); ap[1] = pk(a1.y); ap[2] = pk(a1.z); ap[3] = pk(a1.w);
        ap[4] = pk(a2.x); ap[5] = pk(a2.y); ap[6] = pk(a2.z); ap[7] = pk(a2.w);
    }
    __syncthreads();   // As[0] visible, B(0) DMA drained

    int nk = K >> 6;
    int cur = 0;
    for (int i = 0; i < nk; ++i) {
        float4 a1n, a2n;
        bool more = (i + 1) < nk;
        if (more) {
            int kn = (i + 1) << 6;
            __builtin_amdgcn_global_load_lds((gv_t*)(wsrc + kn),
                (lv_t*)(&Bs[cur ^ 1][0][w * 512]), 16, 0, 0);
            __builtin_amdgcn_global_load_lds((gv_t*)(wsrc + kn + 32),
                (lv_t*)(&Bs[cur ^ 1][1][w * 512]), 16, 0, 0);
            const float* Ap = A + (long)(m0 + sa_m) * K + kn + sa_k;
            a1n = *(const float4*)Ap;
            a2n = *(const float4*)(Ap + 4);
        }
        bfrag af0  = *(const bfrag*)(&As[cur][(wm * 16 + fr_row) * 72 + fr_k]);
        bfrag af1  = *(const bfrag*)(&As[cur][(wm * 16 + fr_row) * 72 + 32 + fr_k]);
        bfrag bg00 = *(const bfrag*)(&Bs[cur][0][(wn * 32 + fr_row) * 32 + fr_k]);
        bfrag bg01 = *(const bfrag*)(&Bs[cur][0][(wn * 32 + 16 + fr_row) * 32 + fr_k]);
        bfrag bg10 = *(const bfrag*)(&Bs[cur][1][(wn * 32 + fr_row) * 32 + fr_k]);
        bfrag bg11 = *(const bfrag*)(&Bs[cur][1][(wn * 32 + 16 + fr_row) * 32 + fr_k]);
        acc[0] = __builtin_amdgcn_mfma_f32_16x16x32_bf16(af0, bg00, acc[0], 0, 0, 0);
        acc[1] = __builtin_amdgcn_mfma_f32_16x16x32_bf16(af0, bg01, acc[1], 0, 0, 0);
        acc[0] = __builtin_amdgcn_mfma_f32_16x16x32_bf16(af1, bg10, acc[0], 0, 0, 0);
        acc[1] = __builtin_amdgcn_mfma_f32_16x16x32_bf16(af1, bg11, acc[1], 0, 0, 0);
        if (more) {
            short* ap = &As[cur ^ 1][sa_m * 72 + sa_k];
            ap[0] = pk(a1n.x); ap[1] = pk(a1n.y); ap[2] = pk(a1n.z); ap[3] = pk(a1n.w);
            ap[4] = pk(a2n.x); ap[5] = pk(a2n.y); ap[6] = pk(a2n.z); ap[7] = pk(a2n.w);
        }
        __syncthreads();   // buffers reusable; next DMA drained (overlapped MFMA)
        cur ^= 1;
    }

    int mbase = (lane >> 4) << 2;
#pragma unroll
    for (int nt = 0; nt < 2; ++nt) {
        int n = n0 + wn * 32 + nt * 16 + (lane & 15);
        float bv = bias ? ((bias2 && n >= 128) ? bias2[n - 128] : bias[n]) : 0.f;
#pragma unroll
        for (int r = 0; r < 4; ++r) {
            int m = m0 + wm * 16 + mbase + r;
            float v = acc[nt][r] + bv;
            if (act == 1) v = fmaxf(v, 0.f);
            else if (act == 2) v = v / (1.f + expf(-v));
            if (res) v += res[(long)m * N + n];
            C[(long)m * N + n] = v;
        }
    }
}

// ---------------------------------------------------------------------------
// fp32 tiled GEMM (small/odd-N) with lda (validated R11).
// ---------------------------------------------------------------------------
__global__ __launch_bounds__(256) void gemm_k(
        const float* __restrict__ A, int lda, const float* __restrict__ W,
        const float* __restrict__ bias, const float* __restrict__ res,
        float* __restrict__ Cf, int M, int K, int Nc, int act) {
    __shared__ __align__(16) float Asf[32][64];
    __shared__ __align__(16) float Bsf[32][64];
    int tid = threadIdx.x;
    int tx = tid & 15, ty = tid >> 4;
    int m0 = blockIdx.x * 64, n0 = blockIdx.y * 64;
    float acc[4][4] = {{0.f}};
    int am = tid >> 2;
    int ak = (tid & 3) << 3;
    int bk = tid >> 4;
    int bn = (tid & 15) << 2;

    for (int k0 = 0; k0 < K; k0 += 32) {
        const float* Ap = A + (long)(m0 + am) * lda + k0 + ak;
        float4 a1 = *(const float4*)Ap;
        float4 a2 = *(const float4*)(Ap + 4);
        float w1[4], w2[4];
#pragma unroll
        for (int u = 0; u < 4; ++u) {
            int n = n0 + bn + u;
            w1[u] = (n < Nc) ? W[(long)(k0 + bk) * Nc + n] : 0.f;
            w2[u] = (n < Nc) ? W[(long)(k0 + bk + 16) * Nc + n] : 0.f;
        }
        __syncthreads();
        Asf[ak + 0][am] = a1.x; Asf[ak + 1][am] = a1.y;
        Asf[ak + 2][am] = a1.z; Asf[ak + 3][am] = a1.w;
        Asf[ak + 4][am] = a2.x; Asf[ak + 5][am] = a2.y;
        Asf[ak + 6][am] = a2.z; Asf[ak + 7][am] = a2.w;
#pragma unroll
        for (int u = 0; u < 4; ++u) {
            Bsf[bk][bn + u] = w1[u];
            Bsf[bk + 16][bn + u] = w2[u];
        }
        __syncthreads();
#pragma unroll
        for (int k = 0; k < 32; ++k) {
            float4 a = *(const float4*)(&Asf[k][ty << 2]);
            float4 b = *(const float4*)(&Bsf[k][tx << 2]);
            acc[0][0] += a.x * b.x; acc[0][1] += a.x * b.y; acc[0][2] += a.x * b.z; acc[0][3] += a.x * b.w;
            acc[1][0] += a.y * b.x; acc[1][1] += a.y * b.y; acc[1][2] += a.y * b.z; acc[1][3] += a.y * b.w;
            acc[2][0] += a.z * b.x; acc[2][1] += a.z * b.y; acc[2][2] += a.z * b.z; acc[2][3] += a.z * b.w;
            acc[3][0] += a.w * b.x; acc[3][1] += a.w * b.y; acc[3][2] += a.w * b.z; acc[3][3] += a.w * b.w;
        }
    }
#pragma unroll
    for (int i = 0; i < 4; ++i) {
        int m = m0 + (ty << 2) + i;
#pragma unroll
        for (int j = 0; j < 4; ++j) {
            int n = n0 + (tx << 2) + j;
            if (n >= Nc) continue;
            float v = acc[i][j];
            if (bias) v += bias[n];
            if (act == 1) v = fmaxf(v, 0.f);
            else if (act == 2) v = v / (1.f + expf(-v));
            if (res) v += res[(long)m * Nc + n];
            Cf[(long)m * Nc + n] = v;
        }
    }
}

// ---------------------------------------------------------------------------
// GINE v13 — R1/R4 structure + async DMA double-buffered E staging.
// WIN R6: 957 -> 890 µs. Unchanged since.
// ---------------------------------------------------------------------------
#define MF(a, b, c) c = __builtin_amdgcn_mfma_f32_16x16x32_bf16(a, b, c, 0, 0, 0)

// Stage one 24x64-short E-tile pair (eh->lds[0..1535], el->lds[2048..3583])
// as 6 DMA chunks of 512 shorts (64 lanes x 16 B). Wave w: chunks w, w+4.
__device__ __forceinline__ void stage_etile(const short* __restrict__ ej_h,
                                            const short* __restrict__ ej_l,
                                            short* lds_base, int w, int lane) {
    {
        int c = w;   // 0..3
        const short* src = (c < 3) ? (ej_h + c * 512) : (ej_l + (c - 3) * 512);
        int doff = (c < 3) ? c * 512 : 2048 + (c - 3) * 512;
        __builtin_amdgcn_global_load_lds((gv_t*)(src + lane * 8),
                                         (lv_t*)(lds_base + doff), 16, 0, 0);
    }
    if (w < 2) {
        int c = w + 4;   // 4,5 -> el chunks 1,2
        const short* src = ej_l + (c - 3) * 512;
        int doff = 2048 + (c - 3) * 512;
        __builtin_amdgcn_global_load_lds((gv_t*)(src + lane * 8),
                                         (lv_t*)(lds_base + doff), 16, 0, 0);
    }
}

__global__ __launch_bounds__(256, 4) void gine4(
        const float* __restrict__ x,
        const float* __restrict__ lattice, const float* __restrict__ geW,
        const float* __restrict__ geb, const short* __restrict__ gewt_h,
        const short* __restrict__ gewt_l, const short* __restrict__ et_h,
        const short* __restrict__ et_l, float* __restrict__ z, int l) {
    __shared__ __align__(16) float xls[24 * 132];  // 12672 B
    __shared__ float basel[128];                   // 512 B
    __shared__ __align__(16) short ebuf[8192];     // 2 x (eh 32r + el 32r) x 64

    int tid = threadIdx.x;
    int lane = tid & 63, w = tid >> 6, quad = lane >> 4, l16 = lane & 15;
    int g = blockIdx.x >> 2;
    int half = (blockIdx.x >> 1) & 1;
    int jh = blockIdx.x & 1;           // j range jh*12 .. jh*12+11

    // ---- stage x half (float4), base ----
    {
        const float4* xg = (const float4*)x;
        for (int idx = tid; idx < 768; idx += 256) {
            int i = idx >> 5, c4 = idx & 31;
            ((float4*)(xls + i * 132))[c4] =
                xg[((long)(g * NP + i) * CC + half * 128) / 4 + c4];
        }
    }
    if (tid < 128) {
        int cg = half * 128 + tid;
        float bv = geb[(long)l * CC + cg];
#pragma unroll
        for (int q = 0; q < 9; ++q)
            bv += lattice[(long)g * 9 + q] * geW[(long)l * 69 * 256 + (long)(60 + q) * 256 + cg];
        basel[tid] = bv;
    }

    // ---- B fragments direct from global (loop-invariant, named scalars) ----
    bfrag bh00, bh01, bh10, bh11, bl00, bl01, bl10, bl11;
    {
        long base = (long)(l * 2 + half) * 8192;   // shorts: 128 rows x 64
        int nrow0 = w * 32 + l16;                  // nt=0
        int nrow1 = w * 32 + 16 + l16;             // nt=1
        const short* p0h = gewt_h + base + nrow0 * 64 + quad * 8;
        const short* p1h = gewt_h + base + nrow1 * 64 + quad * 8;
        const short* p0l = gewt_l + base + nrow0 * 64 + quad * 8;
        const short* p1l = gewt_l + base + nrow1 * 64 + quad * 8;
        bh00 = *(const bfrag*)(p0h);      bh01 = *(const bfrag*)(p0h + 32);
        bh10 = *(const bfrag*)(p1h);      bh11 = *(const bfrag*)(p1h + 32);
        bl00 = *(const bfrag*)(p0l);      bl01 = *(const bfrag*)(p0l + 32);
        bl10 = *(const bfrag*)(p1l);      bl11 = *(const bfrag*)(p1l + 32);
    }

    const short* ehg = et_h + (long)g * (24 * 24 * 64);
    const short* elg = et_l + (long)g * (24 * 24 * 64);
    int j0 = jh * 12;

    // prologue: DMA first tile into buf 0
    stage_etile(ehg + (long)j0 * 1536, elg + (long)j0 * 1536, ebuf, w, lane);
    __syncthreads();   // drains DMA + makes xls/basel visible

    float bse0 = basel[w * 32 + l16];
    float bse1 = basel[w * 32 + 16 + l16];

    int cur = 0;
    for (int jc = 0; jc < 12; ++jc) {
        int j = j0 + jc;
        // issue next tile's DMA into the other buffer (hidden under compute)
        if (jc < 11) {
            stage_etile(ehg + (long)(j + 1) * 1536, elg + (long)(j + 1) * 1536,
                        ebuf + (cur ^ 1) * 4096, w, lane);
        }

        const short* eb = ebuf + cur * 4096;
        int r0 = l16 * 64 + quad * 8;          // mt=0 row offset (shorts)
        int r1 = (16 + l16) * 64 + quad * 8;   // mt=1
        bfrag ah00 = *(const bfrag*)(eb + r0);
        bfrag ah01 = *(const bfrag*)(eb + r0 + 32);
        bfrag ah10 = *(const bfrag*)(eb + r1);
        bfrag ah11 = *(const bfrag*)(eb + r1 + 32);
        bfrag al00 = *(const bfrag*)(eb + 2048 + r0);
        bfrag al01 = *(const bfrag*)(eb + 2048 + r0 + 32);
        bfrag al10 = *(const bfrag*)(eb + 2048 + r1);
        bfrag al11 = *(const bfrag*)(eb + 2048 + r1 + 32);

        ffrag a00 = {}, a01 = {}, a10 = {}, a11 = {};   // acc[mt][nt]
        // mt=0, ks=0
        MF(ah00, bh00, a00); MF(ah00, bl00, a00); MF(al00, bh00, a00);
        MF(ah00, bh10, a01); MF(ah00, bl10, a01); MF(al00, bh10, a01);
        // mt=0, ks=1
        MF(ah01, bh01, a00); MF(ah01, bl01, a00); MF(al01, bh01, a00);
        MF(ah01, bh11, a01); MF(ah01, bl11, a01); MF(al01, bh11, a01);
        // mt=1, ks=0
        MF(ah10, bh00, a10); MF(ah10, bl00, a10); MF(al10, bh00, a10);
        MF(ah10, bh10, a11); MF(ah10, bl10, a11); MF(al10, bh10, a11);
        // mt=1, ks=1
        MF(ah11, bh01, a10); MF(ah11, bl01, a10); MF(al11, bh01, a10);
        MF(ah11, bh11, a11); MF(ah11, bl11, a11); MF(al11, bh11, a11);

        // epilogue: relu + reduce over i, write z[g*24+j][cg]
#pragma unroll
        for (int nt = 0; nt < 2; ++nt) {
            int cl = w * 32 + nt * 16 + l16;
            float bse = nt ? bse1 : bse0;
            ffrag am0 = nt ? a01 : a00;   // mt=0 acc (ibase = quad*4, < 24)
            ffrag am1 = nt ? a11 : a10;   // mt=1 acc (valid only quad<2)
            float part = 0.f;
            {
                int ibase = quad * 4;
#pragma unroll
                for (int r = 0; r < 4; ++r) {
                    float xv = xls[(ibase + r) * 132 + cl];
                    part += fmaxf(xv + bse + am0[r], 0.f);
                }
            }
            if (quad < 2) {
                int ibase = 16 + quad * 4;
#pragma unroll
                for (int r = 0; r < 4; ++r) {
                    float xv = xls[(ibase + r) * 132 + cl];
                    part += fmaxf(xv + bse + am1[r], 0.f);
                }
            }
            part += __shfl_xor(part, 16);
            part += __shfl_xor(part, 32);
            if (lane < 16)
                z[(long)(g * NP + j) * CC + half * 128 + cl] = xls[j * 132 + cl] + part;
        }
        __syncthreads();
        cur ^= 1;
    }
}

// ---------------------------------------------------------------------------
// BN: R7-exact structure (contraction-sensitive expressions pinned to their
// original kernels — R8's relocation attempt shifted absmax one quantum).
// ---------------------------------------------------------------------------
__global__ void bn_stats1(const float* __restrict__ in, float* __restrict__ part) {
    int c = threadIdx.x, b = blockIdx.x;
    float s = 0.f, q = 0.f;
    for (int r = 0; r < 64; ++r) {
        float v = in[(long)(b * 64 + r) * CC + c];
        s += v; q += v * v;
    }
    part[b * 512 + c] = s;
    part[b * 512 + 256 + c] = q;
}
__global__ __launch_bounds__(256) void bn_apply2(
        const float* __restrict__ in, const float* __restrict__ part,
        const float* __restrict__ gma, const float* __restrict__ bta,
        const float* __restrict__ add, float* __restrict__ out) {
    int c = threadIdx.x;
    float s = 0.f, q = 0.f;
    for (int b = 0; b < 96; ++b) { s += part[b * 512 + c]; q += part[b * 512 + 256 + c]; }
    float m = s / (float)NN;
    float var = q / (float)NN - m * m;
    float stats_c = m;
    float stats_rs = rsqrtf(var + 1e-5f);
    float gc = gma[c], bc = bta[c];
    for (int r = blockIdx.x; r < NN; r += 768) {
        long idx = (long)r * CC + c;
        float v = (in[idx] - stats_c) * stats_rs * gc + bc;
        if (add) v += add[idx];
        out[idx] = v;
    }
}

// ---------------------------------------------------------------------------
// Attention v2 (validated R10).
// ---------------------------------------------------------------------------
__global__ __launch_bounds__(256, 2) void attn2(const float* __restrict__ qkv,
                                                float* __restrict__ o) {
    __shared__ __align__(16) float Kl[24 * 4 * 68];
    __shared__ __align__(16) float Vl[24 * 4 * 68];
    __shared__ float S[4 * 24 * 25];
    int tid = threadIdx.x, g = blockIdx.x;

    const float4* qkv4 = (const float4*)(qkv + (long)g * NP * 768);
    for (int idx = tid; idx < 24 * 128; idx += 256) {
        int row = idx >> 7;
        int c4 = idx & 127;
        int isV = c4 >> 6;
        int cc = c4 & 63;
        int h = cc >> 4, d4 = cc & 15;
        float4 val = qkv4[row * 192 + 64 + c4];
        float* dst = (isV ? Vl : Kl) + (row * 4 + h) * 68 + d4 * 4;
        *(float4*)dst = val;
    }
    __syncthreads();

    if (tid < 96) {
        int h = tid & 3, i = tid >> 2;
        const float4* qp = (const float4*)(qkv + ((long)(g * NP + i)) * 768 + h * 64);
        float4 q[16];
#pragma unroll
        for (int k = 0; k < 16; ++k) q[k] = qp[k];
        float sc[24];
        float mx = -1e30f;
        for (int j = 0; j < 24; ++j) {
            const float4* kp = (const float4*)(Kl + (j * 4 + h) * 68);
            float da = 0.f, db = 0.f;
#pragma unroll
            for (int k = 0; k < 16; k += 2) {
                float4 kv = kp[k];
                da += q[k].x * kv.x; da += q[k].y * kv.y;
                da += q[k].z * kv.z; da += q[k].w * kv.w;
                float4 kv2 = kp[k + 1];
                db += q[k + 1].x * kv2.x; db += q[k + 1].y * kv2.y;
                db += q[k + 1].z * kv2.z; db += q[k + 1].w * kv2.w;
            }
            float s = (da + db) * 0.125f;
            sc[j] = s;
            mx = fmaxf(mx, s);
        }
        float sum = 0.f;
#pragma unroll
        for (int j = 0; j < 24; ++j) { float p = expf(sc[j] - mx); sc[j] = p; sum += p; }
        float inv = 1.f / sum;
#pragma unroll
        for (int j = 0; j < 24; ++j) S[(h * 24 + i) * 25 + j] = sc[j] * inv;
    }
    __syncthreads();

    int h = tid >> 6, d = tid & 63;
    for (int i = 0; i < 24; ++i) {
        const float* Sp = S + (h * 24 + i) * 25;
        float a0 = 0.f, a1 = 0.f;
#pragma unroll
        for (int j = 0; j < 24; j += 2) {
            a0 += Sp[j] * Vl[(j * 4 + h) * 68 + d];
            a1 += Sp[j + 1] * Vl[((j + 1) * 4 + h) * 68 + d];
        }
        o[(long)(g * NP + i) * CC + h * 64 + d] = a0 + a1;
    }
}

// ---------------------------------------------------------------------------
__global__ __launch_bounds__(256) void ln_kernel(const float* __restrict__ x,
        const float* __restrict__ gma, const float* __restrict__ bta,
        float* __restrict__ out) {
    __shared__ float red[256];
    int n = blockIdx.x, c = threadIdx.x;
    float v = x[(long)n * CC + c];
    red[c] = v;
    __syncthreads();
    for (int s = 128; s > 0; s >>= 1) { if (c < s) red[c] += red[c + s]; __syncthreads(); }
    float m = red[0] * (1.f / 256.f);
    __syncthreads();
    float dv = v - m;
    red[c] = dv * dv;
    __syncthreads();
    for (int s = 128; s > 0; s >>= 1) { if (c < s) red[c] += red[c + s]; __syncthreads(); }
    float var = red[0] * (1.f / 256.f);
    out[(long)n * CC + c] = dv * rsqrtf(var + 1e-5f) * gma[c] + bta[c];
}

// ---------------------------------------------------------------------------
// Fused lattice head (R11: pool folded in; validated).
// ---------------------------------------------------------------------------
__global__ __launch_bounds__(256) void lat_head(
        const float* __restrict__ hn, const float* __restrict__ W1,
        const float* __restrict__ b1, const float* __restrict__ W2,
        const float* __restrict__ b2, const float* __restrict__ W3,
        float* __restrict__ out) {
    __shared__ float gfl[256];
    __shared__ float h1[128];
    __shared__ float h2[64];
    int g = blockIdx.x, t = threadIdx.x;
    {
        float s = 0.f;
        for (int j = 0; j < NP; ++j) s += hn[(long)(g * NP + j) * CC + t];
        gfl[t] = s * (1.f / 24.f);
    }
    __syncthreads();
    if (t < 128) {
        float acc = 0.f;
        for (int k = 0; k < 256; ++k) acc += gfl[k] * W1[k * 128 + t];
        float v = acc;
        v += b1[t];
        v = v / (1.f + expf(-v));
        h1[t] = v;
    }
    __syncthreads();
    if (t < 64) {
        float acc = 0.f;
        for (int k = 0; k < 128; ++k) acc += h1[k] * W2[k * 64 + t];
        float v = acc;
        v += b2[t];
        v = v / (1.f + expf(-v));
        h2[t] = v;
    }
    __syncthreads();
    if (t < 9) {
        float acc = 0.f;
        for (int k = 0; k < 64; ++k) acc += h2[k] * W3[k * 9 + t];
        out[(long)g * 9 + t] = acc;
    }
}

// ---------------------------------------------------------------------------
static void gemm(hipStream_t st, const float* A, int lda, const float* W,
                 const float* bias, const float* res, float* Cf,
                 int M, int K, int Nc, int act) {
    dim3 grid(M / 64, (Nc + 63) / 64);
    gemm_k<<<grid, 256, 0, st>>>(A, lda, W, bias, res, Cf, M, K, Nc, act);
}

static void gemmM(hipStream_t st, const float* A, const bf* Wt, const float* bias,
                  const float* bias2, const float* res, float* Cf,
                  int M, int K, int N, int act) {
    dim3 grid(M / 32, N / 64);
    gemm_mfma<<<grid, 256, 0, st>>>(A, Wt, bias, bias2, res, Cf, M, K, N, act);
}

static void run_bn(hipStream_t st, const float* in, float* part,
                   const float* g_, const float* b_, const float* add, float* out) {
    bn_stats1<<<96, 256, 0, st>>>(in, part);
    bn_apply2<<<768, 256, 0, st>>>(in, part, g_, b_, add, out);
}

extern "C" void kernel_launch(void* const* d_in, const int* in_sizes, int n_in,
                              void* d_out, int out_size, void* d_ws, size_t ws_size,
                              hipStream_t stream) {
    float* out = (float*)d_out;
    int sigN = out_size < 256 ? out_size : 256;

    static const int EXP_SIZES[46] = {
        256, 18432, 2304, 25600, 131072, 256, 52992, 768, 196608, 768,
        196608, 768, 589824, 2304, 196608, 768, 393216, 1536, 393216, 768,
        768, 768, 768, 768, 768, 768, 256, 256, 32768, 128,
        12800, 100, 32768, 128, 8192, 64, 576, 32768, 128, 8192,
        64, 192, 6144, 6144, 147456, 147456 };
    if (n_in != 46) { signal_k<<<1, 256, 0, stream>>>(out, sigN, 3000.f + 8.f * n_in); return; }
    for (int i = 0; i < 46; ++i)
        if (in_sizes[i] != EXP_SIZES[i]) { signal_k<<<1, 256, 0, stream>>>(out, sigN, 512.f + 8.f * i); return; }
    if (out_size != NN * 100 + GG * 9 + NN * 3) { signal_k<<<1, 256, 0, stream>>>(out, sigN, 7777.f); return; }

    // ---- workspace (R7-exact layout) ----
    char* base = (char*)d_ws;
    float* f32a = (float*)(base + 256);
    float* x  = f32a;                              // N*256
    float* s1 = x  + (size_t)NN * 256;             // N*256
    float* s2 = s1 + (size_t)NN * 256;             // N*256
    float* big = s2 + (size_t)NN * 256;            // N*768
    float* s3 = big + (size_t)NN * 512;            // alias of big's tail (lifetimes audited)
    float* part = big + (size_t)NN * 768;          // 96*512
    float* stats = part + 96 * 512;                // 512 (unused)
    float* gf  = stats + 512;                      // G*256 (unused)
    float* l1b = gf + GG * 256;                    // G*128 (unused)
    float* l2b = l1b + GG * 128;                   // G*64  (unused)
    bf* wt = (bf*)(l2b + GG * 64);                 // bf16 W^T mirrors
    const long O_NA = 0, O_G1 = 131072, O_G2 = 327680, O_AI = 524288,
               O_AO = 1114112, O_M1 = 1310720, O_M2 = 1703936,
               O_TRO = 2097152, O_FC = 2129920, WT_TOT = 2162688;
    short* gewt_h = (short*)(wt + WT_TOT);         // 49152 shorts
    short* gewt_l = gewt_h + 49152;                // 49152 shorts
    short* et_h = gewt_l + 49152;
    short* et_l = et_h + (ETAB_ELEMS + 1024);
    size_t REQ = 256 + ((size_t)NN * 1536 + 96 * 512 + 512 + GG * 448) * 4
               + WT_TOT * 2 + 49152 * 2 * 2
               + ((size_t)ETAB_ELEMS + 1024) * 2 * 2;
    if (ws_size < REQ) { signal_k<<<1, 256, 0, stream>>>(out, sigN, 9999.f); return; }

    const float* t       = (const float*)d_in[0];
    const float* frac    = (const float*)d_in[1];
    const float* lattice = (const float*)d_in[2];
    const float* type_emb = (const float*)d_in[3];

    // combined weight prep (one dispatch for the 9 transposes)
    {
        TArgs ta;
        const int srcIdx[9] = {4, 8, 10, 12, 14, 16, 18, 28, 37};
        const long dof[9]  = {O_NA, O_G1, O_G2, O_AI, O_AO, O_M1, O_M2, O_TRO, O_FC};
        const int Ks[9] = {512, 256, 256, 256, 256, 256, 512, 256, 256};
        const int Ns[9] = {256, 256, 256, 768, 256, 512, 256, 128, 128};
        const int Ls[9] = {1, 3, 3, 3, 3, 3, 3, 1, 1};
        int blk = 0;
        for (int s = 0; s < 9; ++s) {
            ta.src[s] = (const float*)d_in[srcIdx[s]];
            ta.dstOff[s] = dof[s];
            ta.K[s] = Ks[s]; ta.N[s] = Ns[s]; ta.L[s] = Ls[s];
            ta.blk0[s] = blk;
            blk += (Ks[s] * Ns[s] * Ls[s] + 255) / 256;
        }
        ta.blk0[9] = blk;
        transp_all<<<blk, 256, 0, stream>>>(ta, wt);
    }
    prep_gewtab<<<192 + (ETAB_ELEMS + 255) / 256, 256, 0, stream>>>(
        (const float*)d_in[6], gewt_h, gewt_l, frac, et_h, et_l);

    // x0 = concat(type_emb[atoms], time_emb) @ naW + nab  (int-detect folded in)
    build_A<<<(NN * 512 + 255) / 256, 256, 0, stream>>>(t, type_emb,
        (const unsigned int*)d_in[42], big);
    gemmM(stream, big, wt + O_NA, (const float*)d_in[5], nullptr, nullptr, x, NN, 512, 256, 0);

    for (int l = 0; l < LL; ++l) {
        // GINE: s1 = x + aggr
        gine4<<<GG * 4, 256, 0, stream>>>(x, lattice,
            (const float*)d_in[6], (const float*)d_in[7], gewt_h, gewt_l,
            et_h, et_l, s1, l);
        // s2 = silu(s1@gW1+gb1); s3 = s2@gW2+gb2 + x; h1 = BN(s3) -> s2
        gemmM(stream, s1, wt + O_G1 + (long)l * 65536, (const float*)d_in[9]  + l * 256, nullptr, nullptr, s2, NN, 256, 256, 2);
        gemmM(stream, s2, wt + O_G2 + (long)l * 65536, (const float*)d_in[11] + l * 256, nullptr, x, s3, NN, 256, 256, 0);
        run_bn(stream, s3, part, (const float*)d_in[20] + l * 256, (const float*)d_in[21] + l * 256, nullptr, s2);
        // attention: qkv=big; o=s1; s3 = s1@aoW+aob + x; s1 = h1 + BN(s3)
        gemmM(stream, x, wt + O_AI + (long)l * 196608, (const float*)d_in[13] + l * 768, nullptr, nullptr, big, NN, 256, 768, 0);
        attn2<<<GG, 256, 0, stream>>>(big, s1);
        gemmM(stream, s1, wt + O_AO + (long)l * 65536, (const float*)d_in[15] + l * 256, nullptr, x, s3, NN, 256, 256, 0);
        run_bn(stream, s3, part, (const float*)d_in[22] + l * 256, (const float*)d_in[23] + l * 256, s2, s1);
        // MLP: big = relu(s1@mW1+mb1); s3 = big@mW2+mb2 + s1; x = BN(s3)
        gemmM(stream, s1, wt + O_M1 + (long)l * 131072, (const float*)d_in[17] + l * 512, nullptr, nullptr, big, NN, 256, 512, 1);
        gemmM(stream, big, wt + O_M2 + (long)l * 131072, (const float*)d_in[19] + l * 256, nullptr, s1, s3, NN, 512, 256, 0);
        run_bn(stream, s3, part, (const float*)d_in[24] + l * 256, (const float*)d_in[25] + l * 256, nullptr, x);
    }

    ln_kernel<<<NN, 256, 0, stream>>>(x, (const float*)d_in[26], (const float*)d_in[27], s1);

    // heads: combined TRO|FC gemm (adjacent mirrors, concat bias) -> s2 [NN x 256]
    gemmM(stream, s1, wt + O_TRO, (const float*)d_in[29], (const float*)d_in[38],
          nullptr, s2, NN, 256, 256, 2);
    // types_pred -> out[0 : N*100]   (A = s2 cols 0..127, lda=256)
    gemm(stream, s2, 256, (const float*)d_in[30], (const float*)d_in[31], nullptr, out, NN, 128, 100, 0);
    // lattice_pred -> out[N*100 : +G*9]  (pool folded into lat_head)
    lat_head<<<GG, 256, 0, stream>>>(s1, (const float*)d_in[32], (const float*)d_in[33],
        (const float*)d_in[34], (const float*)d_in[35], (const float*)d_in[36],
        out + (size_t)NN * 100);
    // frac_pred -> out[N*100+G*9 : ]  (A = s2 cols 128..255)
    gemm(stream, s2 + 128, 256, (const float*)d_in[39], (const float*)d_in[40], nullptr, s3, NN, 128, 64, 2);
    gemm(stream, s3, 64, (const float*)d_in[41], nullptr, nullptr, out + (size_t)NN * 100 + GG * 9, NN, 64, 3, 0);
}

// Round 14
// 676.248 us; speedup vs baseline: 1.1214x; 1.0477x over previous
//
#include <hip/hip_runtime.h>
#include <hip/hip_bf16.h>
#include <math.h>

#define GG 256
#define NP 24
#define LL 3
#define CC 256
#define NN (GG*NP)   // 6144 nodes
#define HH 4
#define DH 64

typedef __hip_bfloat16 bf;
typedef __attribute__((ext_vector_type(8))) short bfrag;   // 8 bf16 (4 VGPR)
typedef __attribute__((ext_vector_type(4))) float ffrag;   // 4 fp32 acc

__device__ __forceinline__ short pk(float x) {
    union { bf h; short s; } u; u.h = __float2bfloat16(x); return u.s;
}
__device__ __forceinline__ float b2f_s(short x) {
    union { short s; bf h; } u; u.s = x; return __bfloat162float(u.h);
}

typedef __attribute__((address_space(1))) const void gv_t;
typedef __attribute__((address_space(3))) void lv_t;

// ---------------------------------------------------------------------------
__global__ void signal_k(float* out, int n, float val) {
    int i = blockIdx.x * 256 + threadIdx.x;
    if (i < n) out[i] = val;
}

// ---------------------------------------------------------------------------
// prep_all (R14): transp_all + prep_gewtab + build_A in ONE dispatch via
// block-range switch. All three are independent input-only producers; bodies
// VERBATIM (conversion / single-mul / libm only — no fusible mul->add chains;
// sinf/cosf relocation proven bit-exact in R1/R11).
// Blocks [0, blk0[9]): weight transposes. [blk0[9], +37056): gew+etab.
// Rest: build_A (int64-detect folded, R13-validated).
// ---------------------------------------------------------------------------
#define ETAB_ELEMS (GG * 24 * 24 * 64)   // 9437184
#define GEWTAB_BLKS (192 + (ETAB_ELEMS + 255) / 256)   // 37056
#define BUILDA_BLKS ((NN * 512 + 255) / 256)           // 12288

struct TArgs {
    const float* src[9];
    long dstOff[9];
    int K[9], N[9], L[9];
    int blk0[10];
};

__global__ void prep_all(TArgs a, bf* __restrict__ wt,
                         const float* __restrict__ geW, short* __restrict__ wh,
                         short* __restrict__ wl, const float* __restrict__ frac,
                         short* __restrict__ eh, short* __restrict__ el,
                         const float* __restrict__ t,
                         const float* __restrict__ type_emb,
                         const unsigned int* __restrict__ atoms,
                         float* __restrict__ A) {
    __shared__ int ok;
    int bid = blockIdx.x;
    int nT = a.blk0[9];
    if (bid < nT) {
        // ---- transp_all body (verbatim) ----
        int s = 0;
        while (s < 8 && bid >= a.blk0[s + 1]) ++s;
        long idx = (long)(bid - a.blk0[s]) * 256 + threadIdx.x;
        int KN = a.K[s] * a.N[s];
        long sz = (long)KN * a.L[s];
        if (idx >= sz) return;
        int l = (int)(idx / KN);
        int rem = (int)(idx % KN);
        int k = rem / a.N[s], n = rem % a.N[s];
        wt[a.dstOff[s] + (long)l * KN + (long)n * a.K[s] + k] =
            __float2bfloat16(a.src[s][idx]);
    } else if (bid < nT + GEWTAB_BLKS) {
        int b2 = bid - nT;
        if (b2 < 192) {
            // ---- prep_gew body (verbatim) ----
            int idx = b2 * 256 + threadIdx.x;   // 3*2*128*64 = 49152
            if (idx >= 49152) return;
            int k = idx & 63;
            int n = (idx >> 6) & 127;
            int half = (idx >> 13) & 1;
            int l = idx >> 14;
            float v = (k < 60) ? geW[(long)l * 69 * 256 + (long)k * 256 + half * 128 + n] : 0.f;
            short hi = pk(v);
            short lo = pk(v - b2f_s(hi));
            wh[idx] = hi;
            wl[idx] = lo;
        } else {
            // ---- prep_etab body (verbatim) ----
            int idx = (b2 - 192) * 256 + threadIdx.x;
            if (idx >= ETAB_ELEMS) return;
            int k = idx & 63;
            int rem = idx >> 6;           // (g*24 + j)*24 + i
            int i = rem % 24;
            int rem2 = rem / 24;
            int j = rem2 % 24;
            int g = rem2 / 24;
            float val = 0.f;
            if (k < 60) {
                int r = (k < 30) ? k : k - 30;
                int d = r / 10, f = r % 10;
                float fd = frac[g * 72 + j * 3 + d] - frac[g * 72 + i * 3 + d];
                fd -= floorf(fd);
                float ang = 6.283185307179586f * (float)f * fd;
                val = (k < 30) ? sinf(ang) : cosf(ang);
            }
            short hi = pk(val);
            eh[idx] = hi;
            el[idx] = pk(val - b2f_s(hi));
        }
    } else {
        // ---- build_A body (verbatim, R13 int-detect fold) ----
        int b3 = bid - nT - GEWTAB_BLKS;
        if (threadIdx.x == 0) ok = 1;
        __syncthreads();
        if (atoms[2 * threadIdx.x + 1] != 0u) ok = 0;   // benign race
        __syncthreads();
        int i64 = ok;
        int idx = b3 * 256 + threadIdx.x;
        if (idx >= NN * 512) return;
        int n = idx >> 9;
        int k = idx & 511;
        if (k < 256) {
            int aidx = i64 ? (int)atoms[2 * n] : (int)atoms[n];
            A[idx] = type_emb[(long)aidx * CC + k];
        } else {
            int d = k - 256;
            int g = n / NP;
            float tv = t[g];
            int dd = (d < 128) ? d : d - 128;
            float tf = expf(dd * (-9.210340371976184f / 127.0f));
            float ang = tv * tf;
            A[idx] = (d < 128) ? sinf(ang) : cosf(ang);
        }
    }
}

// ---------------------------------------------------------------------------
// MFMA bf16 GEMM — R11 DMA double-buffered (validated, best-known config).
// ---------------------------------------------------------------------------
__global__ __launch_bounds__(256) void gemm_mfma(
        const float* __restrict__ A, const bf* __restrict__ Wt,
        const float* __restrict__ bias, const float* __restrict__ bias2,
        const float* __restrict__ res,
        float* __restrict__ C, int M, int K, int N, int act) {
    __shared__ __align__(16) short As[2][32 * 72];      // 9.2 KB
    __shared__ __align__(16) short Bs[2][2][64 * 32];   // 16 KB
    int tid = threadIdx.x;
    int lane = tid & 63, w = tid >> 6;
    int wm = w & 1, wn = w >> 1;
    int m0 = blockIdx.x * 32, n0 = blockIdx.y * 64;
    ffrag acc[2] = {};   // [nt]
    int sa_m = tid >> 3, sa_k = (tid & 7) << 3;   // 32 rows x 8 floats
    int fr_row = lane & 15, quad = lane >> 4, fr_k = quad << 3;
    int brow = w * 16 + (lane >> 2);              // 4 waves x 16 rows
    int bko = (lane & 3) << 3;                    // 4 lanes x 8 shorts per row
    const short* wsrc = (const short*)Wt + (long)(n0 + brow) * K + bko;

    // prologue: stage tile 0
    {
        const float* Ap = A + (long)(m0 + sa_m) * K + sa_k;
        float4 a1 = *(const float4*)Ap;
        float4 a2 = *(const float4*)(Ap + 4);
        __builtin_amdgcn_global_load_lds((gv_t*)(wsrc), (lv_t*)(&Bs[0][0][w * 512]), 16, 0, 0);
        __builtin_amdgcn_global_load_lds((gv_t*)(wsrc + 32), (lv_t*)(&Bs[0][1][w * 512]), 16, 0, 0);
        short* ap = &As[0][sa_m * 72 + sa_k];
        ap[0] = pk(a1.x); ap[1] = pk(a1.y); ap[2] = pk(a1.z); ap[3] = pk(a1.w);
        ap[4] = pk(a2.x); ap[5] = pk(a2.y); ap[6] = pk(a2.z); ap[7] = pk(a2.w);
    }
    __syncthreads();   // As[0] visible, B(0) DMA drained

    int nk = K >> 6;
    int cur = 0;
    for (int i = 0; i < nk; ++i) {
        float4 a1n, a2n;
        bool more = (i + 1) < nk;
        if (more) {
            int kn = (i + 1) << 6;
            __builtin_amdgcn_global_load_lds((gv_t*)(wsrc + kn),
                (lv_t*)(&Bs[cur ^ 1][0][w * 512]), 16, 0, 0);
            __builtin_amdgcn_global_load_lds((gv_t*)(wsrc + kn + 32),
                (lv_t*)(&Bs[cur ^ 1][1][w * 512]), 16, 0, 0);
            const float* Ap = A + (long)(m0 + sa_m) * K + kn + sa_k;
            a1n = *(const float4*)Ap;
            a2n = *(const float4*)(Ap + 4);
        }
        bfrag af0  = *(const bfrag*)(&As[cur][(wm * 16 + fr_row) * 72 + fr_k]);
        bfrag af1  = *(const bfrag*)(&As[cur][(wm * 16 + fr_row) * 72 + 32 + fr_k]);
        bfrag bg00 = *(const bfrag*)(&Bs[cur][0][(wn * 32 + fr_row) * 32 + fr_k]);
        bfrag bg01 = *(const bfrag*)(&Bs[cur][0][(wn * 32 + 16 + fr_row) * 32 + fr_k]);
        bfrag bg10 = *(const bfrag*)(&Bs[cur][1][(wn * 32 + fr_row) * 32 + fr_k]);
        bfrag bg11 = *(const bfrag*)(&Bs[cur][1][(wn * 32 + 16 + fr_row) * 32 + fr_k]);
        acc[0] = __builtin_amdgcn_mfma_f32_16x16x32_bf16(af0, bg00, acc[0], 0, 0, 0);
        acc[1] = __builtin_amdgcn_mfma_f32_16x16x32_bf16(af0, bg01, acc[1], 0, 0, 0);
        acc[0] = __builtin_amdgcn_mfma_f32_16x16x32_bf16(af1, bg10, acc[0], 0, 0, 0);
        acc[1] = __builtin_amdgcn_mfma_f32_16x16x32_bf16(af1, bg11, acc[1], 0, 0, 0);
        if (more) {
            short* ap = &As[cur ^ 1][sa_m * 72 + sa_k];
            ap[0] = pk(a1n.x); ap[1] = pk(a1n.y); ap[2] = pk(a1n.z); ap[3] = pk(a1n.w);
            ap[4] = pk(a2n.x); ap[5] = pk(a2n.y); ap[6] = pk(a2n.z); ap[7] = pk(a2n.w);
        }
        __syncthreads();   // buffers reusable; next DMA drained (overlapped MFMA)
        cur ^= 1;
    }

    int mbase = (lane >> 4) << 2;
#pragma unroll
    for (int nt = 0; nt < 2; ++nt) {
        int n = n0 + wn * 32 + nt * 16 + (lane & 15);
        float bv = bias ? ((bias2 && n >= 128) ? bias2[n - 128] : bias[n]) : 0.f;
#pragma unroll
        for (int r = 0; r < 4; ++r) {
            int m = m0 + wm * 16 + mbase + r;
            float v = acc[nt][r] + bv;
            if (act == 1) v = fmaxf(v, 0.f);
            else if (act == 2) v = v / (1.f + expf(-v));
            if (res) v += res[(long)m * N + n];
            C[(long)m * N + n] = v;
        }
    }
}

// ---------------------------------------------------------------------------
// gemm_k body as a device function (R14). Text identical to the validated
// gemm_k kernel; parameterized ONLY by addresses (mA0 for A-row base, mOut0
// for output-row base, ldc). Inner `acc += a*b` are single mul->adds that
// contract to fma deterministically in any context (unlike R8's two-mul BN
// chain). res path dropped (all remaining users pass res=nullptr).
// ---------------------------------------------------------------------------
__device__ __forceinline__ void gemm_k_body(
        const float* __restrict__ A, int lda, int mA0,
        const float* __restrict__ W, const float* __restrict__ bias,
        float* __restrict__ Cf, int ldc, int mOut0,
        int n0, int K, int Nc, int act,
        float (*Asf)[64], float (*Bsf)[64], int tid) {
    int tx = tid & 15, ty = tid >> 4;
    float acc[4][4] = {{0.f}};
    int am = tid >> 2;
    int ak = (tid & 3) << 3;
    int bk = tid >> 4;
    int bn = (tid & 15) << 2;

    for (int k0 = 0; k0 < K; k0 += 32) {
        const float* Ap = A + (long)(mA0 + am) * lda + k0 + ak;
        float4 a1 = *(const float4*)Ap;
        float4 a2 = *(const float4*)(Ap + 4);
        float w1[4], w2[4];
#pragma unroll
        for (int u = 0; u < 4; ++u) {
            int n = n0 + bn + u;
            w1[u] = (n < Nc) ? W[(long)(k0 + bk) * Nc + n] : 0.f;
            w2[u] = (n < Nc) ? W[(long)(k0 + bk + 16) * Nc + n] : 0.f;
        }
        __syncthreads();
        Asf[ak + 0][am] = a1.x; Asf[ak + 1][am] = a1.y;
        Asf[ak + 2][am] = a1.z; Asf[ak + 3][am] = a1.w;
        Asf[ak + 4][am] = a2.x; Asf[ak + 5][am] = a2.y;
        Asf[ak + 6][am] = a2.z; Asf[ak + 7][am] = a2.w;
#pragma unroll
        for (int u = 0; u < 4; ++u) {
            Bsf[bk][bn + u] = w1[u];
            Bsf[bk + 16][bn + u] = w2[u];
        }
        __syncthreads();
#pragma unroll
        for (int k = 0; k < 32; ++k) {
            float4 a = *(const float4*)(&Asf[k][ty << 2]);
            float4 b = *(const float4*)(&Bsf[k][tx << 2]);
            acc[0][0] += a.x * b.x; acc[0][1] += a.x * b.y; acc[0][2] += a.x * b.z; acc[0][3] += a.x * b.w;
            acc[1][0] += a.y * b.x; acc[1][1] += a.y * b.y; acc[1][2] += a.y * b.z; acc[1][3] += a.y * b.w;
            acc[2][0] += a.z * b.x; acc[2][1] += a.z * b.y; acc[2][2] += a.z * b.z; acc[2][3] += a.z * b.w;
            acc[3][0] += a.w * b.x; acc[3][1] += a.w * b.y; acc[3][2] += a.w * b.z; acc[3][3] += a.w * b.w;
        }
    }
#pragma unroll
    for (int i = 0; i < 4; ++i) {
        int m = mOut0 + (ty << 2) + i;
#pragma unroll
        for (int j = 0; j < 4; ++j) {
            int n = n0 + (tx << 2) + j;
            if (n >= Nc) continue;
            float v = acc[i][j];
            if (bias) v += bias[n];
            if (act == 1) v = fmaxf(v, 0.f);
            else if (act == 2) v = v / (1.f + expf(-v));
            Cf[(long)m * ldc + n] = v;
        }
    }
}

// ---------------------------------------------------------------------------
// tail_k (R14): types-gemm + (frac gemm1 -> gemm2 fused via fp32 LDS
// intermediate — exact) + lat_head, via block-range switch. 4 dispatches -> 1.
// Blocks 0..191: types (bx=b>>1, by=b&1 — partition order irrelevant).
// Blocks 192..287: frac pair per 64-row strip (stage2 reads the fp32 LDS
// intermediate through a generic pointer — identical values, identical ops).
// Blocks 288..543: lat_head body verbatim (relocation proven R11).
// ---------------------------------------------------------------------------
__global__ __launch_bounds__(256) void tail_k(
        const float* __restrict__ s2, const float* __restrict__ s1,
        const float* __restrict__ W30, const float* __restrict__ b31,
        const float* __restrict__ W39, const float* __restrict__ b40,
        const float* __restrict__ W41,
        const float* __restrict__ lw1, const float* __restrict__ lb1,
        const float* __restrict__ lw2, const float* __restrict__ lb2,
        const float* __restrict__ lw3,
        float* __restrict__ out_types, float* __restrict__ out_lat,
        float* __restrict__ out_frac) {
    __shared__ __align__(16) float Asf[32][64];
    __shared__ __align__(16) float Bsf[32][64];
    __shared__ __align__(16) float Imm[64][64];
    __shared__ float gfl[256];
    __shared__ float h1s[128];
    __shared__ float h2s[64];
    int tid = threadIdx.x;
    int b = blockIdx.x;
    if (b < 192) {
        int bx = b >> 1, by = b & 1;
        gemm_k_body(s2, 256, bx * 64, W30, b31, out_types, 100, bx * 64,
                    by * 64, 128, 100, 0, Asf, Bsf, tid);
    } else if (b < 288) {
        int m0 = (b - 192) * 64;
        // stage 1: Imm = silu(s2[:,128:] @ W39 + b40)   (fp32, exact)
        gemm_k_body(s2 + 128, 256, m0, W39, b40, &Imm[0][0], 64, 0,
                    0, 128, 64, 2, Asf, Bsf, tid);
        __syncthreads();   // Imm writes visible; stage-1 Asf/Bsf reads done
        // stage 2: out_frac = Imm @ W41
        gemm_k_body(&Imm[0][0], 64, 0, W41, nullptr, out_frac, 3, m0,
                    0, 64, 3, 0, Asf, Bsf, tid);
    } else {
        // ---- lat_head body (verbatim, pool folded) ----
        int g = b - 288, t = tid;
        {
            float s = 0.f;
            for (int j = 0; j < NP; ++j) s += s1[(long)(g * NP + j) * CC + t];
            gfl[t] = s * (1.f / 24.f);
        }
        __syncthreads();
        if (t < 128) {
            float acc = 0.f;
            for (int k = 0; k < 256; ++k) acc += gfl[k] * lw1[k * 128 + t];
            float v = acc;
            v += lb1[t];
            v = v / (1.f + expf(-v));
            h1s[t] = v;
        }
        __syncthreads();
        if (t < 64) {
            float acc = 0.f;
            for (int k = 0; k < 128; ++k) acc += h1s[k] * lw2[k * 64 + t];
            float v = acc;
            v += lb2[t];
            v = v / (1.f + expf(-v));
            h2s[t] = v;
        }
        __syncthreads();
        if (t < 9) {
            float acc = 0.f;
            for (int k = 0; k < 64; ++k) acc += h2s[k] * lw3[k * 9 + t];
            out_lat[(long)g * 9 + t] = acc;
        }
    }
}

// ---------------------------------------------------------------------------
// GINE v13 — R1/R4 structure + async DMA double-buffered E staging.
// WIN R6: 957 -> 890 µs. Unchanged since.
// ---------------------------------------------------------------------------
#define MF(a, b, c) c = __builtin_amdgcn_mfma_f32_16x16x32_bf16(a, b, c, 0, 0, 0)

// Stage one 24x64-short E-tile pair (eh->lds[0..1535], el->lds[2048..3583])
// as 6 DMA chunks of 512 shorts (64 lanes x 16 B). Wave w: chunks w, w+4.
__device__ __forceinline__ void stage_etile(const short* __restrict__ ej_h,
                                            const short* __restrict__ ej_l,
                                            short* lds_base, int w, int lane) {
    {
        int c = w;   // 0..3
        const short* src = (c < 3) ? (ej_h + c * 512) : (ej_l + (c - 3) * 512);
        int doff = (c < 3) ? c * 512 : 2048 + (c - 3) * 512;
        __builtin_amdgcn_global_load_lds((gv_t*)(src + lane * 8),
                                         (lv_t*)(lds_base + doff), 16, 0, 0);
    }
    if (w < 2) {
        int c = w + 4;   // 4,5 -> el chunks 1,2
        const short* src = ej_l + (c - 3) * 512;
        int doff = 2048 + (c - 3) * 512;
        __builtin_amdgcn_global_load_lds((gv_t*)(src + lane * 8),
                                         (lv_t*)(lds_base + doff), 16, 0, 0);
    }
}

__global__ __launch_bounds__(256, 4) void gine4(
        const float* __restrict__ x,
        const float* __restrict__ lattice, const float* __restrict__ geW,
        const float* __restrict__ geb, const short* __restrict__ gewt_h,
        const short* __restrict__ gewt_l, const short* __restrict__ et_h,
        const short* __restrict__ et_l, float* __restrict__ z, int l) {
    __shared__ __align__(16) float xls[24 * 132];  // 12672 B
    __shared__ float basel[128];                   // 512 B
    __shared__ __align__(16) short ebuf[8192];     // 2 x (eh 32r + el 32r) x 64

    int tid = threadIdx.x;
    int lane = tid & 63, w = tid >> 6, quad = lane >> 4, l16 = lane & 15;
    int g = blockIdx.x >> 2;
    int half = (blockIdx.x >> 1) & 1;
    int jh = blockIdx.x & 1;           // j range jh*12 .. jh*12+11

    // ---- stage x half (float4), base ----
    {
        const float4* xg = (const float4*)x;
        for (int idx = tid; idx < 768; idx += 256) {
            int i = idx >> 5, c4 = idx & 31;
            ((float4*)(xls + i * 132))[c4] =
                xg[((long)(g * NP + i) * CC + half * 128) / 4 + c4];
        }
    }
    if (tid < 128) {
        int cg = half * 128 + tid;
        float bv = geb[(long)l * CC + cg];
#pragma unroll
        for (int q = 0; q < 9; ++q)
            bv += lattice[(long)g * 9 + q] * geW[(long)l * 69 * 256 + (long)(60 + q) * 256 + cg];
        basel[tid] = bv;
    }

    // ---- B fragments direct from global (loop-invariant, named scalars) ----
    bfrag bh00, bh01, bh10, bh11, bl00, bl01, bl10, bl11;
    {
        long base = (long)(l * 2 + half) * 8192;   // shorts: 128 rows x 64
        int nrow0 = w * 32 + l16;                  // nt=0
        int nrow1 = w * 32 + 16 + l16;             // nt=1
        const short* p0h = gewt_h + base + nrow0 * 64 + quad * 8;
        const short* p1h = gewt_h + base + nrow1 * 64 + quad * 8;
        const short* p0l = gewt_l + base + nrow0 * 64 + quad * 8;
        const short* p1l = gewt_l + base + nrow1 * 64 + quad * 8;
        bh00 = *(const bfrag*)(p0h);      bh01 = *(const bfrag*)(p0h + 32);
        bh10 = *(const bfrag*)(p1h);      bh11 = *(const bfrag*)(p1h + 32);
        bl00 = *(const bfrag*)(p0l);      bl01 = *(const bfrag*)(p0l + 32);
        bl10 = *(const bfrag*)(p1l);      bl11 = *(const bfrag*)(p1l + 32);
    }

    const short* ehg = et_h + (long)g * (24 * 24 * 64);
    const short* elg = et_l + (long)g * (24 * 24 * 64);
    int j0 = jh * 12;

    // prologue: DMA first tile into buf 0
    stage_etile(ehg + (long)j0 * 1536, elg + (long)j0 * 1536, ebuf, w, lane);
    __syncthreads();   // drains DMA + makes xls/basel visible

    float bse0 = basel[w * 32 + l16];
    float bse1 = basel[w * 32 + 16 + l16];

    int cur = 0;
    for (int jc = 0; jc < 12; ++jc) {
        int j = j0 + jc;
        // issue next tile's DMA into the other buffer (hidden under compute)
        if (jc < 11) {
            stage_etile(ehg + (long)(j + 1) * 1536, elg + (long)(j + 1) * 1536,
                        ebuf + (cur ^ 1) * 4096, w, lane);
        }

        const short* eb = ebuf + cur * 4096;
        int r0 = l16 * 64 + quad * 8;          // mt=0 row offset (shorts)
        int r1 = (16 + l16) * 64 + quad * 8;   // mt=1
        bfrag ah00 = *(const bfrag*)(eb + r0);
        bfrag ah01 = *(const bfrag*)(eb + r0 + 32);
        bfrag ah10 = *(const bfrag*)(eb + r1);
        bfrag ah11 = *(const bfrag*)(eb + r1 + 32);
        bfrag al00 = *(const bfrag*)(eb + 2048 + r0);
        bfrag al01 = *(const bfrag*)(eb + 2048 + r0 + 32);
        bfrag al10 = *(const bfrag*)(eb + 2048 + r1);
        bfrag al11 = *(const bfrag*)(eb + 2048 + r1 + 32);

        ffrag a00 = {}, a01 = {}, a10 = {}, a11 = {};   // acc[mt][nt]
        // mt=0, ks=0
        MF(ah00, bh00, a00); MF(ah00, bl00, a00); MF(al00, bh00, a00);
        MF(ah00, bh10, a01); MF(ah00, bl10, a01); MF(al00, bh10, a01);
        // mt=0, ks=1
        MF(ah01, bh01, a00); MF(ah01, bl01, a00); MF(al01, bh01, a00);
        MF(ah01, bh11, a01); MF(ah01, bl11, a01); MF(al01, bh11, a01);
        // mt=1, ks=0
        MF(ah10, bh00, a10); MF(ah10, bl00, a10); MF(al10, bh00, a10);
        MF(ah10, bh10, a11); MF(ah10, bl10, a11); MF(al10, bh10, a11);
        // mt=1, ks=1
        MF(ah11, bh01, a10); MF(ah11, bl01, a10); MF(al11, bh01, a10);
        MF(ah11, bh11, a11); MF(ah11, bl11, a11); MF(al11, bh11, a11);

        // epilogue: relu + reduce over i, write z[g*24+j][cg]
#pragma unroll
        for (int nt = 0; nt < 2; ++nt) {
            int cl = w * 32 + nt * 16 + l16;
            float bse = nt ? bse1 : bse0;
            ffrag am0 = nt ? a01 : a00;   // mt=0 acc (ibase = quad*4, < 24)
            ffrag am1 = nt ? a11 : a10;   // mt=1 acc (valid only quad<2)
            float part = 0.f;
            {
                int ibase = quad * 4;
#pragma unroll
                for (int r = 0; r < 4; ++r) {
                    float xv = xls[(ibase + r) * 132 + cl];
                    part += fmaxf(xv + bse + am0[r], 0.f);
                }
            }
            if (quad < 2) {
                int ibase = 16 + quad * 4;
#pragma unroll
                for (int r = 0; r < 4; ++r) {
                    float xv = xls[(ibase + r) * 132 + cl];
                    part += fmaxf(xv + bse + am1[r], 0.f);
                }
            }
            part += __shfl_xor(part, 16);
            part += __shfl_xor(part, 32);
            if (lane < 16)
                z[(long)(g * NP + j) * CC + half * 128 + cl] = xls[j * 132 + cl] + part;
        }
        __syncthreads();
        cur ^= 1;
    }
}

// ---------------------------------------------------------------------------
// BN: R7-exact structure (contraction-sensitive expressions pinned to their
// original kernels — R8's relocation attempt shifted absmax one quantum).
// ---------------------------------------------------------------------------
__global__ void bn_stats1(const float* __restrict__ in, float* __restrict__ part) {
    int c = threadIdx.x, b = blockIdx.x;
    float s = 0.f, q = 0.f;
    for (int r = 0; r < 64; ++r) {
        float v = in[(long)(b * 64 + r) * CC + c];
        s += v; q += v * v;
    }
    part[b * 512 + c] = s;
    part[b * 512 + 256 + c] = q;
}
__global__ __launch_bounds__(256) void bn_apply2(
        const float* __restrict__ in, const float* __restrict__ part,
        const float* __restrict__ gma, const float* __restrict__ bta,
        const float* __restrict__ add, float* __restrict__ out) {
    int c = threadIdx.x;
    float s = 0.f, q = 0.f;
    for (int b = 0; b < 96; ++b) { s += part[b * 512 + c]; q += part[b * 512 + 256 + c]; }
    float m = s / (float)NN;
    float var = q / (float)NN - m * m;
    float stats_c = m;
    float stats_rs = rsqrtf(var + 1e-5f);
    float gc = gma[c], bc = bta[c];
    for (int r = blockIdx.x; r < NN; r += 768) {
        long idx = (long)r * CC + c;
        float v = (in[idx] - stats_c) * stats_rs * gc + bc;
        if (add) v += add[idx];
        out[idx] = v;
    }
}

// ---------------------------------------------------------------------------
// Attention v2 (validated R10).
// ---------------------------------------------------------------------------
__global__ __launch_bounds__(256, 2) void attn2(const float* __restrict__ qkv,
                                                float* __restrict__ o) {
    __shared__ __align__(16) float Kl[24 * 4 * 68];
    __shared__ __align__(16) float Vl[24 * 4 * 68];
    __shared__ float S[4 * 24 * 25];
    int tid = threadIdx.x, g = blockIdx.x;

    const float4* qkv4 = (const float4*)(qkv + (long)g * NP * 768);
    for (int idx = tid; idx < 24 * 128; idx += 256) {
        int row = idx >> 7;
        int c4 = idx & 127;
        int isV = c4 >> 6;
        int cc = c4 & 63;
        int h = cc >> 4, d4 = cc & 15;
        float4 val = qkv4[row * 192 + 64 + c4];
        float* dst = (isV ? Vl : Kl) + (row * 4 + h) * 68 + d4 * 4;
        *(float4*)dst = val;
    }
    __syncthreads();

    if (tid < 96) {
        int h = tid & 3, i = tid >> 2;
        const float4* qp = (const float4*)(qkv + ((long)(g * NP + i)) * 768 + h * 64);
        float4 q[16];
#pragma unroll
        for (int k = 0; k < 16; ++k) q[k] = qp[k];
        float sc[24];
        float mx = -1e30f;
        for (int j = 0; j < 24; ++j) {
            const float4* kp = (const float4*)(Kl + (j * 4 + h) * 68);
            float da = 0.f, db = 0.f;
#pragma unroll
            for (int k = 0; k < 16; k += 2) {
                float4 kv = kp[k];
                da += q[k].x * kv.x; da += q[k].y * kv.y;
                da += q[k].z * kv.z; da += q[k].w * kv.w;
                float4 kv2 = kp[k + 1];
                db += q[k + 1].x * kv2.x; db += q[k + 1].y * kv2.y;
                db += q[k + 1].z * kv2.z; db += q[k + 1].w * kv2.w;
            }
            float s = (da + db) * 0.125f;
            sc[j] = s;
            mx = fmaxf(mx, s);
        }
        float sum = 0.f;
#pragma unroll
        for (int j = 0; j < 24; ++j) { float p = expf(sc[j] - mx); sc[j] = p; sum += p; }
        float inv = 1.f / sum;
#pragma unroll
        for (int j = 0; j < 24; ++j) S[(h * 24 + i) * 25 + j] = sc[j] * inv;
    }
    __syncthreads();

    int h = tid >> 6, d = tid & 63;
    for (int i = 0; i < 24; ++i) {
        const float* Sp = S + (h * 24 + i) * 25;
        float a0 = 0.f, a1 = 0.f;
#pragma unroll
        for (int j = 0; j < 24; j += 2) {
            a0 += Sp[j] * Vl[(j * 4 + h) * 68 + d];
            a1 += Sp[j + 1] * Vl[((j + 1) * 4 + h) * 68 + d];
        }
        o[(long)(g * NP + i) * CC + h * 64 + d] = a0 + a1;
    }
}

// ---------------------------------------------------------------------------
__global__ __launch_bounds__(256) void ln_kernel(const float* __restrict__ x,
        const float* __restrict__ gma, const float* __restrict__ bta,
        float* __restrict__ out) {
    __shared__ float red[256];
    int n = blockIdx.x, c = threadIdx.x;
    float v = x[(long)n * CC + c];
    red[c] = v;
    __syncthreads();
    for (int s = 128; s > 0; s >>= 1) { if (c < s) red[c] += red[c + s]; __syncthreads(); }
    float m = red[0] * (1.f / 256.f);
    __syncthreads();
    float dv = v - m;
    red[c] = dv * dv;
    __syncthreads();
    for (int s = 128; s > 0; s >>= 1) { if (c < s) red[c] += red[c + s]; __syncthreads(); }
    float var = red[0] * (1.f / 256.f);
    out[(long)n * CC + c] = dv * rsqrtf(var + 1e-5f) * gma[c] + bta[c];
}

// ---------------------------------------------------------------------------
static void gemmM(hipStream_t st, const float* A, const bf* Wt, const float* bias,
                  const float* bias2, const float* res, float* Cf,
                  int M, int K, int N, int act) {
    dim3 grid(M / 32, N / 64);
    gemm_mfma<<<grid, 256, 0, st>>>(A, Wt, bias, bias2, res, Cf, M, K, N, act);
}

static void run_bn(hipStream_t st, const float* in, float* part,
                   const float* g_, const float* b_, const float* add, float* out) {
    bn_stats1<<<96, 256, 0, st>>>(in, part);
    bn_apply2<<<768, 256, 0, st>>>(in, part, g_, b_, add, out);
}

extern "C" void kernel_launch(void* const* d_in, const int* in_sizes, int n_in,
                              void* d_out, int out_size, void* d_ws, size_t ws_size,
                              hipStream_t stream) {
    float* out = (float*)d_out;
    int sigN = out_size < 256 ? out_size : 256;

    static const int EXP_SIZES[46] = {
        256, 18432, 2304, 25600, 131072, 256, 52992, 768, 196608, 768,
        196608, 768, 589824, 2304, 196608, 768, 393216, 1536, 393216, 768,
        768, 768, 768, 768, 768, 768, 256, 256, 32768, 128,
        12800, 100, 32768, 128, 8192, 64, 576, 32768, 128, 8192,
        64, 192, 6144, 6144, 147456, 147456 };
    if (n_in != 46) { signal_k<<<1, 256, 0, stream>>>(out, sigN, 3000.f + 8.f * n_in); return; }
    for (int i = 0; i < 46; ++i)
        if (in_sizes[i] != EXP_SIZES[i]) { signal_k<<<1, 256, 0, stream>>>(out, sigN, 512.f + 8.f * i); return; }
    if (out_size != NN * 100 + GG * 9 + NN * 3) { signal_k<<<1, 256, 0, stream>>>(out, sigN, 7777.f); return; }

    // ---- workspace (R7-exact layout) ----
    char* base = (char*)d_ws;
    float* f32a = (float*)(base + 256);
    float* x  = f32a;                              // N*256
    float* s1 = x  + (size_t)NN * 256;             // N*256
    float* s2 = s1 + (size_t)NN * 256;             // N*256
    float* big = s2 + (size_t)NN * 256;            // N*768
    float* s3 = big + (size_t)NN * 512;            // alias of big's tail (lifetimes audited)
    float* part = big + (size_t)NN * 768;          // 96*512
    float* stats = part + 96 * 512;                // 512 (unused)
    float* gf  = stats + 512;                      // G*256 (unused)
    float* l1b = gf + GG * 256;                    // G*128 (unused)
    float* l2b = l1b + GG * 128;                   // G*64  (unused)
    bf* wt = (bf*)(l2b + GG * 64);                 // bf16 W^T mirrors
    const long O_NA = 0, O_G1 = 131072, O_G2 = 327680, O_AI = 524288,
               O_AO = 1114112, O_M1 = 1310720, O_M2 = 1703936,
               O_TRO = 2097152, O_FC = 2129920, WT_TOT = 2162688;
    short* gewt_h = (short*)(wt + WT_TOT);         // 49152 shorts
    short* gewt_l = gewt_h + 49152;                // 49152 shorts
    short* et_h = gewt_l + 49152;
    short* et_l = et_h + (ETAB_ELEMS + 1024);
    size_t REQ = 256 + ((size_t)NN * 1536 + 96 * 512 + 512 + GG * 448) * 4
               + WT_TOT * 2 + 49152 * 2 * 2
               + ((size_t)ETAB_ELEMS + 1024) * 2 * 2;
    if (ws_size < REQ) { signal_k<<<1, 256, 0, stream>>>(out, sigN, 9999.f); return; }

    const float* t       = (const float*)d_in[0];
    const float* frac    = (const float*)d_in[1];
    const float* lattice = (const float*)d_in[2];
    const float* type_emb = (const float*)d_in[3];

    // combined prep: 9 weight transposes + gew/etab + build_A (one dispatch)
    int nTblk;
    {
        TArgs ta;
        const int srcIdx[9] = {4, 8, 10, 12, 14, 16, 18, 28, 37};
        const long dof[9]  = {O_NA, O_G1, O_G2, O_AI, O_AO, O_M1, O_M2, O_TRO, O_FC};
        const int Ks[9] = {512, 256, 256, 256, 256, 256, 512, 256, 256};
        const int Ns[9] = {256, 256, 256, 768, 256, 512, 256, 128, 128};
        const int Ls[9] = {1, 3, 3, 3, 3, 3, 3, 1, 1};
        int blk = 0;
        for (int s = 0; s < 9; ++s) {
            ta.src[s] = (const float*)d_in[srcIdx[s]];
            ta.dstOff[s] = dof[s];
            ta.K[s] = Ks[s]; ta.N[s] = Ns[s]; ta.L[s] = Ls[s];
            ta.blk0[s] = blk;
            blk += (Ks[s] * Ns[s] * Ls[s] + 255) / 256;
        }
        ta.blk0[9] = blk;
        nTblk = blk;
        prep_all<<<nTblk + GEWTAB_BLKS + BUILDA_BLKS, 256, 0, stream>>>(
            ta, wt, (const float*)d_in[6], gewt_h, gewt_l, frac, et_h, et_l,
            t, type_emb, (const unsigned int*)d_in[42], big);
    }

    // x0 = concat(type_emb[atoms], time_emb) @ naW + nab
    gemmM(stream, big, wt + O_NA, (const float*)d_in[5], nullptr, nullptr, x, NN, 512, 256, 0);

    for (int l = 0; l < LL; ++l) {
        // GINE: s1 = x + aggr
        gine4<<<GG * 4, 256, 0, stream>>>(x, lattice,
            (const float*)d_in[6], (const float*)d_in[7], gewt_h, gewt_l,
            et_h, et_l, s1, l);
        // s2 = silu(s1@gW1+gb1); s3 = s2@gW2+gb2 + x; h1 = BN(s3) -> s2
        gemmM(stream, s1, wt + O_G1 + (long)l * 65536, (const float*)d_in[9]  + l * 256, nullptr, nullptr, s2, NN, 256, 256, 2);
        gemmM(stream, s2, wt + O_G2 + (long)l * 65536, (const float*)d_in[11] + l * 256, nullptr, x, s3, NN, 256, 256, 0);
        run_bn(stream, s3, part, (const float*)d_in[20] + l * 256, (const float*)d_in[21] + l * 256, nullptr, s2);
        // attention: qkv=big; o=s1; s3 = s1@aoW+aob + x; s1 = h1 + BN(s3)
        gemmM(stream, x, wt + O_AI + (long)l * 196608, (const float*)d_in[13] + l * 768, nullptr, nullptr, big, NN, 256, 768, 0);
        attn2<<<GG, 256, 0, stream>>>(big, s1);
        gemmM(stream, s1, wt + O_AO + (long)l * 65536, (const float*)d_in[15] + l * 256, nullptr, x, s3, NN, 256, 256, 0);
        run_bn(stream, s3, part, (const float*)d_in[22] + l * 256, (const float*)d_in[23] + l * 256, s2, s1);
        // MLP: big = relu(s1@mW1+mb1); s3 = big@mW2+mb2 + s1; x = BN(s3)
        gemmM(stream, s1, wt + O_M1 + (long)l * 131072, (const float*)d_in[17] + l * 512, nullptr, nullptr, big, NN, 256, 512, 1);
        gemmM(stream, big, wt + O_M2 + (long)l * 131072, (const float*)d_in[19] + l * 256, nullptr, s1, s3, NN, 512, 256, 0);
        run_bn(stream, s3, part, (const float*)d_in[24] + l * 256, (const float*)d_in[25] + l * 256, nullptr, x);
    }

    ln_kernel<<<NN, 256, 0, stream>>>(x, (const float*)d_in[26], (const float*)d_in[27], s1);

    // heads: combined TRO|FC gemm (adjacent mirrors, concat bias) -> s2 [NN x 256]
    gemmM(stream, s1, wt + O_TRO, (const float*)d_in[29], (const float*)d_in[38],
          nullptr, s2, NN, 256, 256, 2);
    // all remaining head work in ONE dispatch (types / frac-pair / lattice)
    tail_k<<<544, 256, 0, stream>>>(s2, s1,
        (const float*)d_in[30], (const float*)d_in[31],
        (const float*)d_in[39], (const float*)d_in[40], (const float*)d_in[41],
        (const float*)d_in[32], (const float*)d_in[33],
        (const float*)d_in[34], (const float*)d_in[35], (const float*)d_in[36],
        out, out + (size_t)NN * 100, out + (size_t)NN * 100 + GG * 9);
}

// Round 16
// 653.525 us; speedup vs baseline: 1.1604x; 1.0348x over previous
//
#include <hip/hip_runtime.h>
#include <hip/hip_bf16.h>
#include <math.h>

#define GG 256
#define NP 24
#define LL 3
#define CC 256
#define NN (GG*NP)   // 6144 nodes
#define HH 4
#define DH 64

typedef __hip_bfloat16 bf;
typedef __attribute__((ext_vector_type(8))) short bfrag;   // 8 bf16 (4 VGPR)
typedef __attribute__((ext_vector_type(4))) float ffrag;   // 4 fp32 acc

__device__ __forceinline__ short pk(float x) {
    union { bf h; short s; } u; u.h = __float2bfloat16(x); return u.s;
}
__device__ __forceinline__ float b2f_s(short x) {
    union { short s; bf h; } u; u.s = x; return __bfloat162float(u.h);
}

typedef __attribute__((address_space(1))) const void gv_t;
typedef __attribute__((address_space(3))) void lv_t;

// ---------------------------------------------------------------------------
__global__ void signal_k(float* out, int n, float val) {
    int i = blockIdx.x * 256 + threadIdx.x;
    if (i < n) out[i] = val;
}

// ---------------------------------------------------------------------------
// prep_all (R14, validated) + R15 etab f==0 shortcut (IEEE-identical:
// ang=+0.0f always for f=0, sinf(+0)=+0, cosf(0)=1.0f).
// ---------------------------------------------------------------------------
#define ETAB_ELEMS (GG * 24 * 24 * 64)   // 9437184
#define GEWTAB_BLKS (192 + (ETAB_ELEMS + 255) / 256)   // 37056
#define BUILDA_BLKS ((NN * 512 + 255) / 256)           // 12288

struct TArgs {
    const float* src[9];
    long dstOff[9];
    int K[9], N[9], L[9];
    int blk0[10];
};

__global__ void prep_all(TArgs a, bf* __restrict__ wt,
                         const float* __restrict__ geW, short* __restrict__ wh,
                         short* __restrict__ wl, const float* __restrict__ frac,
                         short* __restrict__ eh, short* __restrict__ el,
                         const float* __restrict__ t,
                         const float* __restrict__ type_emb,
                         const unsigned int* __restrict__ atoms,
                         float* __restrict__ A) {
    __shared__ int ok;
    int bid = blockIdx.x;
    int nT = a.blk0[9];
    if (bid < nT) {
        // ---- transp_all body (verbatim) ----
        int s = 0;
        while (s < 8 && bid >= a.blk0[s + 1]) ++s;
        long idx = (long)(bid - a.blk0[s]) * 256 + threadIdx.x;
        int KN = a.K[s] * a.N[s];
        long sz = (long)KN * a.L[s];
        if (idx >= sz) return;
        int l = (int)(idx / KN);
        int rem = (int)(idx % KN);
        int k = rem / a.N[s], n = rem % a.N[s];
        wt[a.dstOff[s] + (long)l * KN + (long)n * a.K[s] + k] =
            __float2bfloat16(a.src[s][idx]);
    } else if (bid < nT + GEWTAB_BLKS) {
        int b2 = bid - nT;
        if (b2 < 192) {
            // ---- prep_gew body (verbatim) ----
            int idx = b2 * 256 + threadIdx.x;   // 3*2*128*64 = 49152
            if (idx >= 49152) return;
            int k = idx & 63;
            int n = (idx >> 6) & 127;
            int half = (idx >> 13) & 1;
            int l = idx >> 14;
            float v = (k < 60) ? geW[(long)l * 69 * 256 + (long)k * 256 + half * 128 + n] : 0.f;
            short hi = pk(v);
            short lo = pk(v - b2f_s(hi));
            wh[idx] = hi;
            wl[idx] = lo;
        } else {
            // ---- prep_etab body (f==0 constants, otherwise verbatim) ----
            int idx = (b2 - 192) * 256 + threadIdx.x;
            if (idx >= ETAB_ELEMS) return;
            int k = idx & 63;
            int rem = idx >> 6;           // (g*24 + j)*24 + i
            int i = rem % 24;
            int rem2 = rem / 24;
            int j = rem2 % 24;
            int g = rem2 / 24;
            float val = 0.f;
            if (k < 60) {
                int r = (k < 30) ? k : k - 30;
                int d = r / 10, f = r % 10;
                if (f == 0) {
                    val = (k < 30) ? 0.f : 1.f;   // == sinf(+0), cosf(+0)
                } else {
                    float fd = frac[g * 72 + j * 3 + d] - frac[g * 72 + i * 3 + d];
                    fd -= floorf(fd);
                    float ang = 6.283185307179586f * (float)f * fd;
                    val = (k < 30) ? sinf(ang) : cosf(ang);
                }
            }
            short hi = pk(val);
            eh[idx] = hi;
            el[idx] = pk(val - b2f_s(hi));
        }
    } else {
        // ---- build_A body (verbatim, R13 int-detect fold) ----
        int b3 = bid - nT - GEWTAB_BLKS;
        if (threadIdx.x == 0) ok = 1;
        __syncthreads();
        if (atoms[2 * threadIdx.x + 1] != 0u) ok = 0;   // benign race
        __syncthreads();
        int i64 = ok;
        int idx = b3 * 256 + threadIdx.x;
        if (idx >= NN * 512) return;
        int n = idx >> 9;
        int k = idx & 511;
        if (k < 256) {
            int aidx = i64 ? (int)atoms[2 * n] : (int)atoms[n];
            A[idx] = type_emb[(long)aidx * CC + k];
        } else {
            int d = k - 256;
            int g = n / NP;
            float tv = t[g];
            int dd = (d < 128) ? d : d - 128;
            float tf = expf(dd * (-9.210340371976184f / 127.0f));
            float ang = tv * tf;
            A[idx] = (d < 128) ? sinf(ang) : cosf(ang);
        }
    }
}

// ---------------------------------------------------------------------------
// gemm_mfma body as device function (R15; relocation contraction-safe,
// proven R9/R10/R11).
// ---------------------------------------------------------------------------
__device__ __forceinline__ void gemm_mfma_body(
        const float* __restrict__ A, const bf* __restrict__ Wt,
        const float* __restrict__ bias, const float* __restrict__ bias2,
        const float* __restrict__ res, float* __restrict__ C,
        int K, int N, int act, int m0, int n0,
        short (*As)[32 * 72], short (*Bs)[2][64 * 32], int tid) {
    int lane = tid & 63, w = tid >> 6;
    int wm = w & 1, wn = w >> 1;
    ffrag acc[2] = {};   // [nt]
    int sa_m = tid >> 3, sa_k = (tid & 7) << 3;   // 32 rows x 8 floats
    int fr_row = lane & 15, quad = lane >> 4, fr_k = quad << 3;
    int brow = w * 16 + (lane >> 2);              // 4 waves x 16 rows
    int bko = (lane & 3) << 3;                    // 4 lanes x 8 shorts per row
    const short* wsrc = (const short*)Wt + (long)(n0 + brow) * K + bko;

    // prologue: stage tile 0
    {
        const float* Ap = A + (long)(m0 + sa_m) * K + sa_k;
        float4 a1 = *(const float4*)Ap;
        float4 a2 = *(const float4*)(Ap + 4);
        __builtin_amdgcn_global_load_lds((gv_t*)(wsrc), (lv_t*)(&Bs[0][0][w * 512]), 16, 0, 0);
        __builtin_amdgcn_global_load_lds((gv_t*)(wsrc + 32), (lv_t*)(&Bs[0][1][w * 512]), 16, 0, 0);
        short* ap = &As[0][sa_m * 72 + sa_k];
        ap[0] = pk(a1.x); ap[1] = pk(a1.y); ap[2] = pk(a1.z); ap[3] = pk(a1.w);
        ap[4] = pk(a2.x); ap[5] = pk(a2.y); ap[6] = pk(a2.z); ap[7] = pk(a2.w);
    }
    __syncthreads();   // As[0] visible, B(0) DMA drained

    int nk = K >> 6;
    int cur = 0;
    for (int i = 0; i < nk; ++i) {
        float4 a1n, a2n;
        bool more = (i + 1) < nk;
        if (more) {
            int kn = (i + 1) << 6;
            __builtin_amdgcn_global_load_lds((gv_t*)(wsrc + kn),
                (lv_t*)(&Bs[cur ^ 1][0][w * 512]), 16, 0, 0);
            __builtin_amdgcn_global_load_lds((gv_t*)(wsrc + kn + 32),
                (lv_t*)(&Bs[cur ^ 1][1][w * 512]), 16, 0, 0);
            const float* Ap = A + (long)(m0 + sa_m) * K + kn + sa_k;
            a1n = *(const float4*)Ap;
            a2n = *(const float4*)(Ap + 4);
        }
        bfrag af0  = *(const bfrag*)(&As[cur][(wm * 16 + fr_row) * 72 + fr_k]);
        bfrag af1  = *(const bfrag*)(&As[cur][(wm * 16 + fr_row) * 72 + 32 + fr_k]);
        bfrag bg00 = *(const bfrag*)(&Bs[cur][0][(wn * 32 + fr_row) * 32 + fr_k]);
        bfrag bg01 = *(const bfrag*)(&Bs[cur][0][(wn * 32 + 16 + fr_row) * 32 + fr_k]);
        bfrag bg10 = *(const bfrag*)(&Bs[cur][1][(wn * 32 + fr_row) * 32 + fr_k]);
        bfrag bg11 = *(const bfrag*)(&Bs[cur][1][(wn * 32 + 16 + fr_row) * 32 + fr_k]);
        acc[0] = __builtin_amdgcn_mfma_f32_16x16x32_bf16(af0, bg00, acc[0], 0, 0, 0);
        acc[1] = __builtin_amdgcn_mfma_f32_16x16x32_bf16(af0, bg01, acc[1], 0, 0, 0);
        acc[0] = __builtin_amdgcn_mfma_f32_16x16x32_bf16(af1, bg10, acc[0], 0, 0, 0);
        acc[1] = __builtin_amdgcn_mfma_f32_16x16x32_bf16(af1, bg11, acc[1], 0, 0, 0);
        if (more) {
            short* ap = &As[cur ^ 1][sa_m * 72 + sa_k];
            ap[0] = pk(a1n.x); ap[1] = pk(a1n.y); ap[2] = pk(a1n.z); ap[3] = pk(a1n.w);
            ap[4] = pk(a2n.x); ap[5] = pk(a2n.y); ap[6] = pk(a2n.z); ap[7] = pk(a2n.w);
        }
        __syncthreads();   // buffers reusable; next DMA drained (overlapped MFMA)
        cur ^= 1;
    }

    int mbase = (lane >> 4) << 2;
#pragma unroll
    for (int nt = 0; nt < 2; ++nt) {
        int n = n0 + wn * 32 + nt * 16 + (lane & 15);
        float bv = bias ? ((bias2 && n >= 128) ? bias2[n - 128] : bias[n]) : 0.f;
#pragma unroll
        for (int r = 0; r < 4; ++r) {
            int m = m0 + wm * 16 + mbase + r;
            float v = acc[nt][r] + bv;
            if (act == 1) v = fmaxf(v, 0.f);
            else if (act == 2) v = v / (1.f + expf(-v));
            if (res) v += res[(long)m * N + n];
            C[(long)m * N + n] = v;
        }
    }
}

__global__ __launch_bounds__(256) void gemm_mfma(
        const float* __restrict__ A, const bf* __restrict__ Wt,
        const float* __restrict__ bias, const float* __restrict__ bias2,
        const float* __restrict__ res,
        float* __restrict__ C, int M, int K, int N, int act) {
    __shared__ __align__(16) short As[2][32 * 72];
    __shared__ __align__(16) short Bs[2][2][64 * 32];
    gemm_mfma_body(A, Wt, bias, bias2, res, C, K, N, act,
                   blockIdx.x * 32, blockIdx.y * 64, As, Bs, threadIdx.x);
}

// ---------------------------------------------------------------------------
// apply_ai (R16): bn1's apply + AI qkv gemm in ONE dispatch. R15's failure
// was an ALIAS RACE (s3 overlapped big's tail; the gemm clobbered the apply's
// input) — fixed by giving s3 a dedicated buffer. The two halves now touch
// disjoint memory: gemm reads x/wt -> writes big; apply reads s3/part ->
// writes s2 (s2 not consumed until bn2's apply). apply body VERBATIM
// (relocation precedent R7). absmax is the contraction tripwire.
// ---------------------------------------------------------------------------
__global__ __launch_bounds__(256) void apply_ai(
        const float* __restrict__ Ag, const bf* __restrict__ Wt,
        const float* __restrict__ bias, float* __restrict__ C, int K, int N,
        const float* __restrict__ in, const float* __restrict__ part,
        const float* __restrict__ gma, const float* __restrict__ bta,
        const float* __restrict__ add, float* __restrict__ out) {
    __shared__ __align__(16) short As[2][32 * 72];
    __shared__ __align__(16) short Bs[2][2][64 * 32];
    int b = blockIdx.x;
    int nb = N / 64;
    int ng = (NN / 32) * nb;
    if (b < ng) {
        gemm_mfma_body(Ag, Wt, bias, nullptr, nullptr, C, K, N, 0,
                       (b / nb) * 32, (b % nb) * 64, As, Bs, threadIdx.x);
    } else {
        int bb = b - ng;
        int c = threadIdx.x;
        float s = 0.f, q = 0.f;
        for (int b2 = 0; b2 < 96; ++b2) { s += part[b2 * 512 + c]; q += part[b2 * 512 + 256 + c]; }
        float m = s / (float)NN;
        float var = q / (float)NN - m * m;
        float stats_c = m;
        float stats_rs = rsqrtf(var + 1e-5f);
        float gc = gma[c], bc = bta[c];
        for (int r = bb; r < NN; r += 768) {
            long idx = (long)r * CC + c;
            float v = (in[idx] - stats_c) * stats_rs * gc + bc;
            if (add) v += add[idx];
            out[idx] = v;
        }
    }
}

// ---------------------------------------------------------------------------
// gemm_k body as device function (R14, validated).
// ---------------------------------------------------------------------------
__device__ __forceinline__ void gemm_k_body(
        const float* __restrict__ A, int lda, int mA0,
        const float* __restrict__ W, const float* __restrict__ bias,
        float* __restrict__ Cf, int ldc, int mOut0,
        int n0, int K, int Nc, int act,
        float (*Asf)[64], float (*Bsf)[64], int tid) {
    int tx = tid & 15, ty = tid >> 4;
    float acc[4][4] = {{0.f}};
    int am = tid >> 2;
    int ak = (tid & 3) << 3;
    int bk = tid >> 4;
    int bn = (tid & 15) << 2;

    for (int k0 = 0; k0 < K; k0 += 32) {
        const float* Ap = A + (long)(mA0 + am) * lda + k0 + ak;
        float4 a1 = *(const float4*)Ap;
        float4 a2 = *(const float4*)(Ap + 4);
        float w1[4], w2[4];
#pragma unroll
        for (int u = 0; u < 4; ++u) {
            int n = n0 + bn + u;
            w1[u] = (n < Nc) ? W[(long)(k0 + bk) * Nc + n] : 0.f;
            w2[u] = (n < Nc) ? W[(long)(k0 + bk + 16) * Nc + n] : 0.f;
        }
        __syncthreads();
        Asf[ak + 0][am] = a1.x; Asf[ak + 1][am] = a1.y;
        Asf[ak + 2][am] = a1.z; Asf[ak + 3][am] = a1.w;
        Asf[ak + 4][am] = a2.x; Asf[ak + 5][am] = a2.y;
        Asf[ak + 6][am] = a2.z; Asf[ak + 7][am] = a2.w;
#pragma unroll
        for (int u = 0; u < 4; ++u) {
            Bsf[bk][bn + u] = w1[u];
            Bsf[bk + 16][bn + u] = w2[u];
        }
        __syncthreads();
#pragma unroll
        for (int k = 0; k < 32; ++k) {
            float4 a = *(const float4*)(&Asf[k][ty << 2]);
            float4 b = *(const float4*)(&Bsf[k][tx << 2]);
            acc[0][0] += a.x * b.x; acc[0][1] += a.x * b.y; acc[0][2] += a.x * b.z; acc[0][3] += a.x * b.w;
            acc[1][0] += a.y * b.x; acc[1][1] += a.y * b.y; acc[1][2] += a.y * b.z; acc[1][3] += a.y * b.w;
            acc[2][0] += a.z * b.x; acc[2][1] += a.z * b.y; acc[2][2] += a.z * b.z; acc[2][3] += a.z * b.w;
            acc[3][0] += a.w * b.x; acc[3][1] += a.w * b.y; acc[3][2] += a.w * b.z; acc[3][3] += a.w * b.w;
        }
    }
#pragma unroll
    for (int i = 0; i < 4; ++i) {
        int m = mOut0 + (ty << 2) + i;
#pragma unroll
        for (int j = 0; j < 4; ++j) {
            int n = n0 + (tx << 2) + j;
            if (n >= Nc) continue;
            float v = acc[i][j];
            if (bias) v += bias[n];
            if (act == 1) v = fmaxf(v, 0.f);
            else if (act == 2) v = v / (1.f + expf(-v));
            Cf[(long)m * ldc + n] = v;
        }
    }
}

// ---------------------------------------------------------------------------
// tail_k (R14, validated): types + frac-pair + lat_head in one dispatch.
// ---------------------------------------------------------------------------
__global__ __launch_bounds__(256) void tail_k(
        const float* __restrict__ s2, const float* __restrict__ s1,
        const float* __restrict__ W30, const float* __restrict__ b31,
        const float* __restrict__ W39, const float* __restrict__ b40,
        const float* __restrict__ W41,
        const float* __restrict__ lw1, const float* __restrict__ lb1,
        const float* __restrict__ lw2, const float* __restrict__ lb2,
        const float* __restrict__ lw3,
        float* __restrict__ out_types, float* __restrict__ out_lat,
        float* __restrict__ out_frac) {
    __shared__ __align__(16) float Asf[32][64];
    __shared__ __align__(16) float Bsf[32][64];
    __shared__ __align__(16) float Imm[64][64];
    __shared__ float gfl[256];
    __shared__ float h1s[128];
    __shared__ float h2s[64];
    int tid = threadIdx.x;
    int b = blockIdx.x;
    if (b < 192) {
        int bx = b >> 1, by = b & 1;
        gemm_k_body(s2, 256, bx * 64, W30, b31, out_types, 100, bx * 64,
                    by * 64, 128, 100, 0, Asf, Bsf, tid);
    } else if (b < 288) {
        int m0 = (b - 192) * 64;
        gemm_k_body(s2 + 128, 256, m0, W39, b40, &Imm[0][0], 64, 0,
                    0, 128, 64, 2, Asf, Bsf, tid);
        __syncthreads();
        gemm_k_body(&Imm[0][0], 64, 0, W41, nullptr, out_frac, 3, m0,
                    0, 64, 3, 0, Asf, Bsf, tid);
    } else {
        int g = b - 288, t = tid;
        {
            float s = 0.f;
            for (int j = 0; j < NP; ++j) s += s1[(long)(g * NP + j) * CC + t];
            gfl[t] = s * (1.f / 24.f);
        }
        __syncthreads();
        if (t < 128) {
            float acc = 0.f;
            for (int k = 0; k < 256; ++k) acc += gfl[k] * lw1[k * 128 + t];
            float v = acc;
            v += lb1[t];
            v = v / (1.f + expf(-v));
            h1s[t] = v;
        }
        __syncthreads();
        if (t < 64) {
            float acc = 0.f;
            for (int k = 0; k < 128; ++k) acc += h1s[k] * lw2[k * 64 + t];
            float v = acc;
            v += lb2[t];
            v = v / (1.f + expf(-v));
            h2s[t] = v;
        }
        __syncthreads();
        if (t < 9) {
            float acc = 0.f;
            for (int k = 0; k < 64; ++k) acc += h2s[k] * lw3[k * 9 + t];
            out_lat[(long)g * 9 + t] = acc;
        }
    }
}

// ---------------------------------------------------------------------------
// GINE v13 — R1/R4 structure + async DMA double-buffered E staging.
// WIN R6: 957 -> 890 µs. Unchanged since.
// ---------------------------------------------------------------------------
#define MF(a, b, c) c = __builtin_amdgcn_mfma_f32_16x16x32_bf16(a, b, c, 0, 0, 0)

__device__ __forceinline__ void stage_etile(const short* __restrict__ ej_h,
                                            const short* __restrict__ ej_l,
                                            short* lds_base, int w, int lane) {
    {
        int c = w;   // 0..3
        const short* src = (c < 3) ? (ej_h + c * 512) : (ej_l + (c - 3) * 512);
        int doff = (c < 3) ? c * 512 : 2048 + (c - 3) * 512;
        __builtin_amdgcn_global_load_lds((gv_t*)(src + lane * 8),
                                         (lv_t*)(lds_base + doff), 16, 0, 0);
    }
    if (w < 2) {
        int c = w + 4;   // 4,5 -> el chunks 1,2
        const short* src = ej_l + (c - 3) * 512;
        int doff = 2048 + (c - 3) * 512;
        __builtin_amdgcn_global_load_lds((gv_t*)(src + lane * 8),
                                         (lv_t*)(lds_base + doff), 16, 0, 0);
    }
}

__global__ __launch_bounds__(256, 4) void gine4(
        const float* __restrict__ x,
        const float* __restrict__ lattice, const float* __restrict__ geW,
        const float* __restrict__ geb, const short* __restrict__ gewt_h,
        const short* __restrict__ gewt_l, const short* __restrict__ et_h,
        const short* __restrict__ et_l, float* __restrict__ z, int l) {
    __shared__ __align__(16) float xls[24 * 132];  // 12672 B
    __shared__ float basel[128];                   // 512 B
    __shared__ __align__(16) short ebuf[8192];     // 2 x (eh 32r + el 32r) x 64

    int tid = threadIdx.x;
    int lane = tid & 63, w = tid >> 6, quad = lane >> 4, l16 = lane & 15;
    int g = blockIdx.x >> 2;
    int half = (blockIdx.x >> 1) & 1;
    int jh = blockIdx.x & 1;           // j range jh*12 .. jh*12+11

    // ---- stage x half (float4), base ----
    {
        const float4* xg = (const float4*)x;
        for (int idx = tid; idx < 768; idx += 256) {
            int i = idx >> 5, c4 = idx & 31;
            ((float4*)(xls + i * 132))[c4] =
                xg[((long)(g * NP + i) * CC + half * 128) / 4 + c4];
        }
    }
    if (tid < 128) {
        int cg = half * 128 + tid;
        float bv = geb[(long)l * CC + cg];
#pragma unroll
        for (int q = 0; q < 9; ++q)
            bv += lattice[(long)g * 9 + q] * geW[(long)l * 69 * 256 + (long)(60 + q) * 256 + cg];
        basel[tid] = bv;
    }

    // ---- B fragments direct from global (loop-invariant, named scalars) ----
    bfrag bh00, bh01, bh10, bh11, bl00, bl01, bl10, bl11;
    {
        long base = (long)(l * 2 + half) * 8192;   // shorts: 128 rows x 64
        int nrow0 = w * 32 + l16;                  // nt=0
        int nrow1 = w * 32 + 16 + l16;             // nt=1
        const short* p0h = gewt_h + base + nrow0 * 64 + quad * 8;
        const short* p1h = gewt_h + base + nrow1 * 64 + quad * 8;
        const short* p0l = gewt_l + base + nrow0 * 64 + quad * 8;
        const short* p1l = gewt_l + base + nrow1 * 64 + quad * 8;
        bh00 = *(const bfrag*)(p0h);      bh01 = *(const bfrag*)(p0h + 32);
        bh10 = *(const bfrag*)(p1h);      bh11 = *(const bfrag*)(p1h + 32);
        bl00 = *(const bfrag*)(p0l);      bl01 = *(const bfrag*)(p0l + 32);
        bl10 = *(const bfrag*)(p1l);      bl11 = *(const bfrag*)(p1l + 32);
    }

    const short* ehg = et_h + (long)g * (24 * 24 * 64);
    const short* elg = et_l + (long)g * (24 * 24 * 64);
    int j0 = jh * 12;

    // prologue: DMA first tile into buf 0
    stage_etile(ehg + (long)j0 * 1536, elg + (long)j0 * 1536, ebuf, w, lane);
    __syncthreads();   // drains DMA + makes xls/basel visible

    float bse0 = basel[w * 32 + l16];
    float bse1 = basel[w * 32 + 16 + l16];

    int cur = 0;
    for (int jc = 0; jc < 12; ++jc) {
        int j = j0 + jc;
        if (jc < 11) {
            stage_etile(ehg + (long)(j + 1) * 1536, elg + (long)(j + 1) * 1536,
                        ebuf + (cur ^ 1) * 4096, w, lane);
        }

        const short* eb = ebuf + cur * 4096;
        int r0 = l16 * 64 + quad * 8;          // mt=0 row offset (shorts)
        int r1 = (16 + l16) * 64 + quad * 8;   // mt=1
        bfrag ah00 = *(const bfrag*)(eb + r0);
        bfrag ah01 = *(const bfrag*)(eb + r0 + 32);
        bfrag ah10 = *(const bfrag*)(eb + r1);
        bfrag ah11 = *(const bfrag*)(eb + r1 + 32);
        bfrag al00 = *(const bfrag*)(eb + 2048 + r0);
        bfrag al01 = *(const bfrag*)(eb + 2048 + r0 + 32);
        bfrag al10 = *(const bfrag*)(eb + 2048 + r1);
        bfrag al11 = *(const bfrag*)(eb + 2048 + r1 + 32);

        ffrag a00 = {}, a01 = {}, a10 = {}, a11 = {};   // acc[mt][nt]
        // mt=0, ks=0
        MF(ah00, bh00, a00); MF(ah00, bl00, a00); MF(al00, bh00, a00);
        MF(ah00, bh10, a01); MF(ah00, bl10, a01); MF(al00, bh10, a01);
        // mt=0, ks=1
        MF(ah01, bh01, a00); MF(ah01, bl01, a00); MF(al01, bh01, a00);
        MF(ah01, bh11, a01); MF(ah01, bl11, a01); MF(al01, bh11, a01);
        // mt=1, ks=0
        MF(ah10, bh00, a10); MF(ah10, bl00, a10); MF(al10, bh00, a10);
        MF(ah10, bh10, a11); MF(ah10, bl10, a11); MF(al10, bh10, a11);
        // mt=1, ks=1
        MF(ah11, bh01, a10); MF(ah11, bl01, a10); MF(al11, bh01, a10);
        MF(ah11, bh11, a11); MF(ah11, bl11, a11); MF(al11, bh11, a11);

        // epilogue: relu + reduce over i, write z[g*24+j][cg]
#pragma unroll
        for (int nt = 0; nt < 2; ++nt) {
            int cl = w * 32 + nt * 16 + l16;
            float bse = nt ? bse1 : bse0;
            ffrag am0 = nt ? a01 : a00;   // mt=0 acc (ibase = quad*4, < 24)
            ffrag am1 = nt ? a11 : a10;   // mt=1 acc (valid only quad<2)
            float part = 0.f;
            {
                int ibase = quad * 4;
#pragma unroll
                for (int r = 0; r < 4; ++r) {
                    float xv = xls[(ibase + r) * 132 + cl];
                    part += fmaxf(xv + bse + am0[r], 0.f);
                }
            }
            if (quad < 2) {
                int ibase = 16 + quad * 4;
#pragma unroll
                for (int r = 0; r < 4; ++r) {
                    float xv = xls[(ibase + r) * 132 + cl];
                    part += fmaxf(xv + bse + am1[r], 0.f);
                }
            }
            part += __shfl_xor(part, 16);
            part += __shfl_xor(part, 32);
            if (lane < 16)
                z[(long)(g * NP + j) * CC + half * 128 + cl] = xls[j * 132 + cl] + part;
        }
        __syncthreads();
        cur ^= 1;
    }
}

// ---------------------------------------------------------------------------
// BN: R7-exact structure (contraction-sensitive expressions pinned).
// ---------------------------------------------------------------------------
__global__ void bn_stats1(const float* __restrict__ in, float* __restrict__ part) {
    int c = threadIdx.x, b = blockIdx.x;
    float s = 0.f, q = 0.f;
    for (int r = 0; r < 64; ++r) {
        float v = in[(long)(b * 64 + r) * CC + c];
        s += v; q += v * v;
    }
    part[b * 512 + c] = s;
    part[b * 512 + 256 + c] = q;
}
__global__ __launch_bounds__(256) void bn_apply2(
        const float* __restrict__ in, const float* __restrict__ part,
        const float* __restrict__ gma, const float* __restrict__ bta,
        const float* __restrict__ add, float* __restrict__ out) {
    int c = threadIdx.x;
    float s = 0.f, q = 0.f;
    for (int b = 0; b < 96; ++b) { s += part[b * 512 + c]; q += part[b * 512 + 256 + c]; }
    float m = s / (float)NN;
    float var = q / (float)NN - m * m;
    float stats_c = m;
    float stats_rs = rsqrtf(var + 1e-5f);
    float gc = gma[c], bc = bta[c];
    for (int r = blockIdx.x; r < NN; r += 768) {
        long idx = (long)r * CC + c;
        float v = (in[idx] - stats_c) * stats_rs * gc + bc;
        if (add) v += add[idx];
        out[idx] = v;
    }
}

// ---------------------------------------------------------------------------
// Attention v2 (validated R10).
// ---------------------------------------------------------------------------
__global__ __launch_bounds__(256, 2) void attn2(const float* __restrict__ qkv,
                                                float* __restrict__ o) {
    __shared__ __align__(16) float Kl[24 * 4 * 68];
    __shared__ __align__(16) float Vl[24 * 4 * 68];
    __shared__ float S[4 * 24 * 25];
    int tid = threadIdx.x, g = blockIdx.x;

    const float4* qkv4 = (const float4*)(qkv + (long)g * NP * 768);
    for (int idx = tid; idx < 24 * 128; idx += 256) {
        int row = idx >> 7;
        int c4 = idx & 127;
        int isV = c4 >> 6;
        int cc = c4 & 63;
        int h = cc >> 4, d4 = cc & 15;
        float4 val = qkv4[row * 192 + 64 + c4];
        float* dst = (isV ? Vl : Kl) + (row * 4 + h) * 68 + d4 * 4;
        *(float4*)dst = val;
    }
    __syncthreads();

    if (tid < 96) {
        int h = tid & 3, i = tid >> 2;
        const float4* qp = (const float4*)(qkv + ((long)(g * NP + i)) * 768 + h * 64);
        float4 q[16];
#pragma unroll
        for (int k = 0; k < 16; ++k) q[k] = qp[k];
        float sc[24];
        float mx = -1e30f;
        for (int j = 0; j < 24; ++j) {
            const float4* kp = (const float4*)(Kl + (j * 4 + h) * 68);
            float da = 0.f, db = 0.f;
#pragma unroll
            for (int k = 0; k < 16; k += 2) {
                float4 kv = kp[k];
                da += q[k].x * kv.x; da += q[k].y * kv.y;
                da += q[k].z * kv.z; da += q[k].w * kv.w;
                float4 kv2 = kp[k + 1];
                db += q[k + 1].x * kv2.x; db += q[k + 1].y * kv2.y;
                db += q[k + 1].z * kv2.z; db += q[k + 1].w * kv2.w;
            }
            float s = (da + db) * 0.125f;
            sc[j] = s;
            mx = fmaxf(mx, s);
        }
        float sum = 0.f;
#pragma unroll
        for (int j = 0; j < 24; ++j) { float p = expf(sc[j] - mx); sc[j] = p; sum += p; }
        float inv = 1.f / sum;
#pragma unroll
        for (int j = 0; j < 24; ++j) S[(h * 24 + i) * 25 + j] = sc[j] * inv;
    }
    __syncthreads();

    int h = tid >> 6, d = tid & 63;
    for (int i = 0; i < 24; ++i) {
        const float* Sp = S + (h * 24 + i) * 25;
        float a0 = 0.f, a1 = 0.f;
#pragma unroll
        for (int j = 0; j < 24; j += 2) {
            a0 += Sp[j] * Vl[(j * 4 + h) * 68 + d];
            a1 += Sp[j + 1] * Vl[((j + 1) * 4 + h) * 68 + d];
        }
        o[(long)(g * NP + i) * CC + h * 64 + d] = a0 + a1;
    }
}

// ---------------------------------------------------------------------------
__global__ __launch_bounds__(256) void ln_kernel(const float* __restrict__ x,
        const float* __restrict__ gma, const float* __restrict__ bta,
        float* __restrict__ out) {
    __shared__ float red[256];
    int n = blockIdx.x, c = threadIdx.x;
    float v = x[(long)n * CC + c];
    red[c] = v;
    __syncthreads();
    for (int s = 128; s > 0; s >>= 1) { if (c < s) red[c] += red[c + s]; __syncthreads(); }
    float m = red[0] * (1.f / 256.f);
    __syncthreads();
    float dv = v - m;
    red[c] = dv * dv;
    __syncthreads();
    for (int s = 128; s > 0; s >>= 1) { if (c < s) red[c] += red[c + s]; __syncthreads(); }
    float var = red[0] * (1.f / 256.f);
    out[(long)n * CC + c] = dv * rsqrtf(var + 1e-5f) * gma[c] + bta[c];
}

// ---------------------------------------------------------------------------
static void gemmM(hipStream_t st, const float* A, const bf* Wt, const float* bias,
                  const float* bias2, const float* res, float* Cf,
                  int M, int K, int N, int act) {
    dim3 grid(M / 32, N / 64);
    gemm_mfma<<<grid, 256, 0, st>>>(A, Wt, bias, bias2, res, Cf, M, K, N, act);
}

static void run_bn(hipStream_t st, const float* in, float* part,
                   const float* g_, const float* b_, const float* add, float* out) {
    bn_stats1<<<96, 256, 0, st>>>(in, part);
    bn_apply2<<<768, 256, 0, st>>>(in, part, g_, b_, add, out);
}

extern "C" void kernel_launch(void* const* d_in, const int* in_sizes, int n_in,
                              void* d_out, int out_size, void* d_ws, size_t ws_size,
                              hipStream_t stream) {
    float* out = (float*)d_out;
    int sigN = out_size < 256 ? out_size : 256;

    static const int EXP_SIZES[46] = {
        256, 18432, 2304, 25600, 131072, 256, 52992, 768, 196608, 768,
        196608, 768, 589824, 2304, 196608, 768, 393216, 1536, 393216, 768,
        768, 768, 768, 768, 768, 768, 256, 256, 32768, 128,
        12800, 100, 32768, 128, 8192, 64, 576, 32768, 128, 8192,
        64, 192, 6144, 6144, 147456, 147456 };
    if (n_in != 46) { signal_k<<<1, 256, 0, stream>>>(out, sigN, 3000.f + 8.f * n_in); return; }
    for (int i = 0; i < 46; ++i)
        if (in_sizes[i] != EXP_SIZES[i]) { signal_k<<<1, 256, 0, stream>>>(out, sigN, 512.f + 8.f * i); return; }
    if (out_size != NN * 100 + GG * 9 + NN * 3) { signal_k<<<1, 256, 0, stream>>>(out, sigN, 7777.f); return; }

    // ---- workspace (R16: s3 now a DEDICATED buffer — no alias with big) ----
    char* base = (char*)d_ws;
    float* f32a = (float*)(base + 256);
    float* x  = f32a;                              // N*256
    float* s1 = x  + (size_t)NN * 256;             // N*256
    float* s2 = s1 + (size_t)NN * 256;             // N*256
    float* big = s2 + (size_t)NN * 256;            // N*768
    float* s3 = big + (size_t)NN * 768;            // N*256 (dedicated, R16)
    float* part = s3 + (size_t)NN * 256;           // 96*512
    bf* wt = (bf*)(part + 96 * 512);               // bf16 W^T mirrors
    const long O_NA = 0, O_G1 = 131072, O_G2 = 327680, O_AI = 524288,
               O_AO = 1114112, O_M1 = 1310720, O_M2 = 1703936,
               O_TRO = 2097152, O_FC = 2129920, WT_TOT = 2162688;
    short* gewt_h = (short*)(wt + WT_TOT);         // 49152 shorts
    short* gewt_l = gewt_h + 49152;                // 49152 shorts
    short* et_h = gewt_l + 49152;
    short* et_l = et_h + (ETAB_ELEMS + 1024);
    size_t REQ = 256 + ((size_t)NN * 1792 + 96 * 512) * 4
               + WT_TOT * 2 + 49152 * 2 * 2
               + ((size_t)ETAB_ELEMS + 1024) * 2 * 2;
    if (ws_size < REQ) { signal_k<<<1, 256, 0, stream>>>(out, sigN, 9999.f); return; }

    const float* t       = (const float*)d_in[0];
    const float* frac    = (const float*)d_in[1];
    const float* lattice = (const float*)d_in[2];
    const float* type_emb = (const float*)d_in[3];

    // combined prep: 9 weight transposes + gew/etab + build_A (one dispatch)
    int nTblk;
    {
        TArgs ta;
        const int srcIdx[9] = {4, 8, 10, 12, 14, 16, 18, 28, 37};
        const long dof[9]  = {O_NA, O_G1, O_G2, O_AI, O_AO, O_M1, O_M2, O_TRO, O_FC};
        const int Ks[9] = {512, 256, 256, 256, 256, 256, 512, 256, 256};
        const int Ns[9] = {256, 256, 256, 768, 256, 512, 256, 128, 128};
        const int Ls[9] = {1, 3, 3, 3, 3, 3, 3, 1, 1};
        int blk = 0;
        for (int s = 0; s < 9; ++s) {
            ta.src[s] = (const float*)d_in[srcIdx[s]];
            ta.dstOff[s] = dof[s];
            ta.K[s] = Ks[s]; ta.N[s] = Ns[s]; ta.L[s] = Ls[s];
            ta.blk0[s] = blk;
            blk += (Ks[s] * Ns[s] * Ls[s] + 255) / 256;
        }
        ta.blk0[9] = blk;
        nTblk = blk;
        prep_all<<<nTblk + GEWTAB_BLKS + BUILDA_BLKS, 256, 0, stream>>>(
            ta, wt, (const float*)d_in[6], gewt_h, gewt_l, frac, et_h, et_l,
            t, type_emb, (const unsigned int*)d_in[42], big);
    }

    // x0 = concat(type_emb[atoms], time_emb) @ naW + nab
    gemmM(stream, big, wt + O_NA, (const float*)d_in[5], nullptr, nullptr, x, NN, 512, 256, 0);

    for (int l = 0; l < LL; ++l) {
        // GINE: s1 = x + aggr
        gine4<<<GG * 4, 256, 0, stream>>>(x, lattice,
            (const float*)d_in[6], (const float*)d_in[7], gewt_h, gewt_l,
            et_h, et_l, s1, l);
        // s2 = silu(s1@gW1+gb1); s3 = s2@gW2+gb2 + x
        gemmM(stream, s1, wt + O_G1 + (long)l * 65536, (const float*)d_in[9]  + l * 256, nullptr, nullptr, s2, NN, 256, 256, 2);
        gemmM(stream, s2, wt + O_G2 + (long)l * 65536, (const float*)d_in[11] + l * 256, nullptr, x, s3, NN, 256, 256, 0);
        // bn1 stats; then {bn1 apply -> s2} MERGED with {AI qkv gemm -> big}
        // (disjoint memory now: s3 is dedicated, no overlap with big)
        bn_stats1<<<96, 256, 0, stream>>>(s3, part);
        apply_ai<<<(NN / 32) * 12 + 768, 256, 0, stream>>>(
            x, wt + O_AI + (long)l * 196608, (const float*)d_in[13] + l * 768, big, 256, 768,
            s3, part, (const float*)d_in[20] + l * 256, (const float*)d_in[21] + l * 256,
            nullptr, s2);
        attn2<<<GG, 256, 0, stream>>>(big, s1);
        gemmM(stream, s1, wt + O_AO + (long)l * 65536, (const float*)d_in[15] + l * 256, nullptr, x, s3, NN, 256, 256, 0);
        run_bn(stream, s3, part, (const float*)d_in[22] + l * 256, (const float*)d_in[23] + l * 256, s2, s1);
        // MLP: big = relu(s1@mW1+mb1); s3 = big@mW2+mb2 + s1; x = BN(s3)
        gemmM(stream, s1, wt + O_M1 + (long)l * 131072, (const float*)d_in[17] + l * 512, nullptr, nullptr, big, NN, 256, 512, 1);
        gemmM(stream, big, wt + O_M2 + (long)l * 131072, (const float*)d_in[19] + l * 256, nullptr, s1, s3, NN, 512, 256, 0);
        run_bn(stream, s3, part, (const float*)d_in[24] + l * 256, (const float*)d_in[25] + l * 256, nullptr, x);
    }

    ln_kernel<<<NN, 256, 0, stream>>>(x, (const float*)d_in[26], (const float*)d_in[27], s1);

    // heads: combined TRO|FC gemm (adjacent mirrors, concat bias) -> s2 [NN x 256]
    gemmM(stream, s1, wt + O_TRO, (const float*)d_in[29], (const float*)d_in[38],
          nullptr, s2, NN, 256, 256, 2);
    // all remaining head work in ONE dispatch (types / frac-pair / lattice)
    tail_k<<<544, 256, 0, stream>>>(s2, s1,
        (const float*)d_in[30], (const float*)d_in[31],
        (const float*)d_in[39], (const float*)d_in[40], (const float*)d_in[41],
        (const float*)d_in[32], (const float*)d_in[33],
        (const float*)d_in[34], (const float*)d_in[35], (const float*)d_in[36],
        out, out + (size_t)NN * 100, out + (size_t)NN * 100 + GG * 9);
}